// Round 2
// baseline (1427.582 us; speedup 1.0000x reference)
//
#include <hip/hip_runtime.h>
#include <math.h>

#define N 8192
#define H 128
#define BB 100
#define KK 5
#define MAXN 256
#define TD_MAXF 10000.0f

// ---------------------------------------------------------------------------
// prep: transpose Wh/Ws/Wr (H x H) to k-major; pack om0_w|om1_w contiguously.
// No pointer selects (if/else chains only) to dodge the gfx950 ISel bug.
__global__ __launch_bounds__(256) void prep_weights_kernel(
    const float* __restrict__ Wh, const float* __restrict__ Ws,
    const float* __restrict__ Wr, const float* __restrict__ om0,
    const float* __restrict__ om1, float* __restrict__ WhT,
    float* __restrict__ WsT, float* __restrict__ WrT, float* __restrict__ omP) {
  int idx = blockIdx.x * 256 + threadIdx.x;
  if (idx < H * H) {
    int d = idx >> 7, k = idx & (H - 1);
    WhT[k * H + d] = Wh[d * H + k];
  } else if (idx < 2 * H * H) {
    int e = idx - H * H;
    int d = e >> 7, k = e & (H - 1);
    WsT[k * H + d] = Ws[d * H + k];
  } else if (idx < 3 * H * H) {
    int e = idx - 2 * H * H;
    int d = e >> 7, k = e & (H - 1);
    WrT[k * H + d] = Wr[d * H + k];
  } else if (idx < 3 * H * H + 2 * H) {
    int e = idx - 3 * H * H;
    omP[e] = om0[e];
  } else if (idx < 3 * H * H + 4 * H) {
    int e = idx - 3 * H * H - 2 * H;
    omP[2 * H + e] = om1[e];
  }
}

// prep: copy z0 -> workspace z (float4)
__global__ __launch_bounds__(256) void copyz_kernel(const float* __restrict__ z0,
                                                    float* __restrict__ zws) {
  int i = blockIdx.x * 256 + threadIdx.x;
  if (i < N * H / 4) ((float4*)zws)[i] = ((const float4*)z0)[i];
}

// prep: base per-node dots with omega halves (from z0).
// dvec layout: [dL0 | dR0 | dL1 | dR1], each N floats.
__global__ __launch_bounds__(256) void dbase_kernel(
    const float* __restrict__ z0, const float* __restrict__ om0,
    const float* __restrict__ om1, float* __restrict__ dvec) {
  int j = blockIdx.x * 256 + threadIdx.x;
  if (j >= N) return;
  const float4* zr = (const float4*)(z0 + (size_t)j * H);
  const float4* o0 = (const float4*)om0;
  const float4* o1 = (const float4*)om1;
  float a0 = 0, b0 = 0, a1 = 0, b1 = 0;
  for (int k = 0; k < H / 4; ++k) {
    float4 zv = zr[k];
    float4 l0 = o0[k], r0 = o0[k + H / 4];
    float4 l1 = o1[k], r1 = o1[k + H / 4];
    a0 += zv.x * l0.x + zv.y * l0.y + zv.z * l0.z + zv.w * l0.w;
    b0 += zv.x * r0.x + zv.y * r0.y + zv.z * r0.z + zv.w * r0.w;
    a1 += zv.x * l1.x + zv.y * l1.y + zv.z * l1.z + zv.w * l1.w;
    b1 += zv.x * r1.x + zv.y * r1.y + zv.z * r1.z + zv.w * r1.w;
  }
  dvec[0 * N + j] = a0;
  dvec[1 * N + j] = b0;
  dvec[2 * N + j] = a1;
  dvec[3 * N + j] = b1;
}

// prep: WhAll = z0 @ Wh.T + Wh_b for all N rows
__global__ __launch_bounds__(128) void whall_kernel(
    const float* __restrict__ z0, const float* __restrict__ WhT,
    const float* __restrict__ Wh_b, float* __restrict__ whall) {
  int n = blockIdx.x;
  __shared__ float zr[H];
  zr[threadIdx.x] = z0[(size_t)n * H + threadIdx.x];
  __syncthreads();
  int d = threadIdx.x;
  float acc = Wh_b[d];
#pragma unroll 8
  for (int k = 0; k < H; ++k) acc += zr[k] * WhT[k * H + d];
  whall[(size_t)n * H + d] = acc;
}

// prep: neighbor lists for the 2B struct() calls. list l = 2*b + r,
// r=0 -> node v[b] (hs row 0), r=1 -> node u[b] (hs row 1).
// Atomic-free: per-thread count -> serial exclusive scan -> deterministic write.
__global__ __launch_bounds__(256) void nbr_kernel(
    const int* __restrict__ u, const int* __restrict__ v,
    const float* __restrict__ A, const float* __restrict__ S,
    int* __restrict__ cnt, int* __restrict__ nidx, float* __restrict__ nes,
    float* __restrict__ qsum) {
  int l = blockIdx.x;
  int b = l >> 1, r = l & 1;
  int node = r ? u[b] : v[b];
  const int tid = threadIdx.x;
  __shared__ int cnts[256];
  __shared__ int excl[257];
  __shared__ float ssum[256];
  int c = 0;
  float local = 0.0f;
  for (int it = 0; it < N / 256; ++it) {
    int j = it * 256 + tid;
    if (A[(size_t)node * N + j] > 0.0f) {
      ++c;
      local += expf(S[(size_t)node * N + j]);
    }
  }
  cnts[tid] = c;
  ssum[tid] = local;
  __syncthreads();
  if (tid == 0) {
    int s = 0;
    for (int i = 0; i < 256; ++i) { excl[i] = s; s += cnts[i]; }
    excl[256] = s;
  }
  __syncthreads();
  int p = excl[tid];
  for (int it = 0; it < N / 256; ++it) {
    int j = it * 256 + tid;
    if (A[(size_t)node * N + j] > 0.0f) {
      if (p < MAXN) {
        nidx[l * MAXN + p] = j;
        nes[l * MAXN + p] = expf(S[(size_t)node * N + j]);
      }
      ++p;
    }
  }
  __syncthreads();
  for (int s = 128; s > 0; s >>= 1) {
    if (tid < s) ssum[tid] += ssum[tid + s];
    __syncthreads();
  }
  if (tid == 0) {
    cnt[l] = min(excl[256], MAXN);
    qsum[l] = ssum[0];
  }
}

// ---------------------------------------------------------------------------
// sequential scan: ONE block, loops b = 0..B-1
__global__ __launch_bounds__(1024) void seq_kernel(
    const int* __restrict__ u_, const int* __restrict__ v_,
    const int* __restrict__ et_, const int* __restrict__ neg_,
    const float* __restrict__ time_diff, const float* __restrict__ t_bar,
    const float* __restrict__ t_, const float* __restrict__ omP,
    const float* __restrict__ om0_b, const float* __restrict__ om1_b,
    const float* __restrict__ Wh_b, const float* __restrict__ Ws_b,
    const float* __restrict__ Wr_b, const float* __restrict__ Wt_w,
    const float* __restrict__ Wt_b, const float* __restrict__ w_t,
    const float* __restrict__ alpha, const float* __restrict__ psi, float* zws,
    float* whall, const float* __restrict__ WhT, const float* __restrict__ WsT,
    const float* __restrict__ WrT, float* dvec, float* lamD, float* su_sv,
    const float* __restrict__ qsum_, const int* __restrict__ cnt_,
    const int* __restrict__ nidx_, const float* __restrict__ nes_, float* out) {
  const int t = threadIdx.x;
  __shared__ float hsS[2][H];
  __shared__ float zrowS[2][H];
  __shared__ float zupdS[2][H];
  __shared__ float smax[2][4][H];
  __shared__ float hpart[8][2][H];
  __shared__ float td2S[2][4];
  __shared__ int uS, vS, eS;
  __shared__ float tS, tbuS, tbvS, psS, alS, wtS, obS;

  for (int b = 0; b < BB; ++b) {
    if (t == 0) {
      int ub = u_[b], vb = v_[b], e = et_[b];
      uS = ub; vS = vb; eS = e;
      tS = t_[b];
      tbuS = t_bar[(size_t)b * N + ub];
      tbvS = t_bar[(size_t)b * N + vb];
      psS = psi[e]; alS = alpha[e]; wtS = w_t[e];
      float ob0 = om0_b[0], ob1 = om1_b[0];
      obS = e ? ob1 : ob0;
    }
    if (t < 8) {
      int c = t & 3;
      float sd = (c == 0) ? 50.0f : ((c == 1) ? 7.0f : 15.0f);
      td2S[t >> 2][c] = time_diff[b * 8 + t] / sd;
    }
    __syncthreads();

    const int ub = uS, vb = vS, e = eS;
    const size_t offL = (size_t)(2 * e) * N;   // dL_e
    const size_t offR = offL + N;              // dR_e
    const float ps = psS, al = alS, wt = wtS, ob = obS;
    const float tcur = tS;

    // P1a: lam_pos (col 0) and lam_neg (cols 1..10) -- pre-update d arrays
    if (t < 11) {
      int li, ri; float ltu, ltv;
      if (t == 0) { li = ub; ri = vb; ltu = tbuS; ltv = tbvS; }
      else if (t <= 5) {
        int vn = neg_[b * (2 * KK) + (t - 1)];
        li = ub; ri = vn; ltu = tbuS; ltv = t_bar[(size_t)b * N + vn];
      } else {
        int un = neg_[b * (2 * KK) + (t - 1)];
        li = un; ri = vb; ltu = t_bar[(size_t)b * N + un]; ltv = tbvS;
      }
      float g = dvec[offL + li] + dvec[offR + ri] + ob;
      float gp = fminf(fmaxf(g / (ps + 1e-7f), -75.0f), 75.0f);
      float ts = tcur - fmaxf(ltu, ltv);
      out[b * 12 + t] = ps * log1pf(expf(gp)) + al * expf(-wt * (ts / TD_MAXF));
    } else if (t == 11) {
      su_sv[2 * b] = dvec[offL + ub];      // dot(z_u, om_et[:H]) pre-update
      su_sv[2 * b + 1] = dvec[offL + vb];  // dot(z_v, om_et[:H]) pre-update
    }
    // P1b: snapshot dR_et -> lamD row b (rows u,v are masked downstream)
    {
      const float4* src = (const float4*)(dvec + offR);
      float4* dst = (float4*)(lamD + (size_t)b * N);
      for (int i = t; i < N / 4; i += 1024) dst[i] = src[i];
    }
    // P1d: stage z_u, z_v (pre-update)
    if (t < 2 * H) {
      int r = t >> 7, d = t & (H - 1);
      int node = r ? vb : ub;
      zrowS[r][d] = zws[(size_t)node * H + d];
    }
    // P1c: struct() partial max over neighbors (sigmoid monotone: max
    // pre-activation, sigmoid once)
    {
      int r = t >> 9;
      int sub = (t >> 7) & 3;
      int d = t & (H - 1);
      int l = 2 * b + r;
      int c = cnt_[l];
      float invq = 1.0f / (qsum_[l] + 1e-7f);
      float mx = -INFINITY;
      for (int i = sub; i < c; i += 4) {
        int n = nidx_[l * MAXN + i];
        float q = nes_[l * MAXN + i] * invq;
        mx = fmaxf(mx, q * whall[(size_t)n * H + d]);
      }
      smax[r][sub][d] = mx;
    }
    __syncthreads();
    // P2: combine struct max -> hs
    if (t < 2 * H) {
      int r = t >> 7, d = t & (H - 1);
      int l = 2 * b + r;
      float m = fmaxf(fmaxf(smax[r][0][d], smax[r][1][d]),
                      fmaxf(smax[r][2][d], smax[r][3][d]));
      hsS[r][d] = (cnt_[l] > 0) ? (1.0f / (1.0f + expf(-m))) : 0.0f;
    }
    __syncthreads();
    // P3: h = hs@Ws.T + zrow@Wr.T (k-split across 8 groups)
    {
      int ks = t >> 7;
      int d = t & (H - 1);
      int k0 = ks * 16;
      float a0 = 0.0f, a1 = 0.0f;
#pragma unroll 4
      for (int k = k0; k < k0 + 16; ++k) {
        float ws = WsT[k * H + d], wr = WrT[k * H + d];
        a0 += hsS[0][k] * ws + zrowS[0][k] * wr;
        a1 += hsS[1][k] * ws + zrowS[1][k] * wr;
      }
      hpart[ks][0][d] = a0;
      hpart[ks][1][d] = a1;
    }
    __syncthreads();
    // P4: combine + biases + Wt*td2 -> z_upd = sigmoid(h)
    if (t < 2 * H) {
      int r = t >> 7, d = t & (H - 1);
      float acc = 0.0f;
#pragma unroll
      for (int ks = 0; ks < 8; ++ks) acc += hpart[ks][r][d];
      acc += Ws_b[d] + Wr_b[d] + Wt_b[d];
      acc += td2S[r][0] * Wt_w[d * 4 + 0] + td2S[r][1] * Wt_w[d * 4 + 1] +
             td2S[r][2] * Wt_w[d * 4 + 2] + td2S[r][3] * Wt_w[d * 4 + 3];
      zupdS[r][d] = 1.0f / (1.0f + expf(-acc));
    }
    __syncthreads();
    // P5/P6: z[u] then z[v] (v wins when u==v, as in .at[u].set().at[v].set())
    if (t < H) zws[(size_t)ub * H + t] = zupdS[0][t];
    __syncthreads();
    if (t < H) zws[(size_t)vb * H + t] = zupdS[1][t];
    __syncthreads();
    // P7: refresh WhAll rows u,v from the NEW z rows
    {
      int ks = t >> 7;
      int d = t & (H - 1);
      int k0 = ks * 16;
      int r0 = (ub == vb) ? 1 : 0;  // final z[u] is zupd[1] when u==v
      float a0 = 0.0f, a1 = 0.0f;
#pragma unroll 4
      for (int k = k0; k < k0 + 16; ++k) {
        float wh = WhT[k * H + d];
        a0 += zupdS[r0][k] * wh;
        a1 += zupdS[1][k] * wh;
      }
      hpart[ks][0][d] = a0;
      hpart[ks][1][d] = a1;
    }
    __syncthreads();
    // P8a: store WhAll rows; P8b: refresh dL/dR for rows u,v
    if (t < 2 * H) {
      int r = t >> 7, d = t & (H - 1);
      int node = r ? vb : ub;
      float acc = Wh_b[d];
#pragma unroll
      for (int ks = 0; ks < 8; ++ks) acc += hpart[ks][r][d];
      whall[(size_t)node * H + d] = acc;
    } else if (t < 768) {
      int w = (t - 256) >> 6;  // 8 waves: (row, which-dot)
      int lane = t & 63;
      int row = w >> 2;
      int which = w & 3;  // 0:dL0 1:dR0 2:dL1 3:dR1
      int rr = (row == 0 && ub == vb) ? 1 : row;
      int wsel = which >> 1;       // omega 0 or 1
      int off = (which & 1) * H;   // L or R half
      float val = zupdS[rr][lane] * omP[wsel * 2 * H + off + lane] +
                  zupdS[rr][64 + lane] * omP[wsel * 2 * H + off + 64 + lane];
      for (int s = 32; s > 0; s >>= 1) val += __shfl_down(val, s);
      if (lane == 0) {
        int node = row ? vb : ub;
        dvec[(size_t)which * N + node] = val;
      }
    }
    __syncthreads();
  }
}

// ---------------------------------------------------------------------------
// parallel lam_sum: one block per step b over the snapshot lamD[b]
__global__ __launch_bounds__(256) void lam_kernel(
    const int* __restrict__ u, const int* __restrict__ v,
    const int* __restrict__ etypes, const float* __restrict__ t_bar,
    const float* __restrict__ tt, const float* __restrict__ w_t,
    const float* __restrict__ alpha, const float* __restrict__ psi,
    const float* __restrict__ om0_b, const float* __restrict__ om1_b,
    const float* __restrict__ lamD, const float* __restrict__ su_sv,
    float* __restrict__ out) {
  int b = blockIdx.x;
  int ub = u[b], vb = v[b], e = etypes[b];
  float ps = psi[e], al = alpha[e], wt = w_t[e];
  float ob0 = om0_b[0], ob1 = om1_b[0];
  float ob = e ? ob1 : ob0;
  float su = su_sv[2 * b], sv = su_sv[2 * b + 1];
  float tb_u = t_bar[(size_t)b * N + ub], tb_v = t_bar[(size_t)b * N + vb];
  float tcur = tt[b];
  float inv_ps = 1.0f / (ps + 1e-7f);
  float acc = 0.0f;
  for (int j = threadIdx.x; j < N; j += 256) {
    if (j == ub || j == vb) continue;
    float d = lamD[(size_t)b * N + j];
    float tbj = t_bar[(size_t)b * N + j];
    float gu = su + d + ob;
    float gv = sv + d + ob;
    float gpu_ = fminf(fmaxf(gu * inv_ps, -75.0f), 75.0f);
    float gpv_ = fminf(fmaxf(gv * inv_ps, -75.0f), 75.0f);
    float spl = ps * (log1pf(expf(gpu_)) + log1pf(expf(gpv_)));
    float tdu = tcur - fmaxf(tb_u, tbj);
    float tdv = tcur - fmaxf(tb_v, tbj);
    float ex = al * (expf(-wt * (tdu / TD_MAXF)) + expf(-wt * (tdv / TD_MAXF)));
    acc += spl + ex;
  }
  __shared__ float red[256];
  red[threadIdx.x] = acc;
  __syncthreads();
  for (int s = 128; s > 0; s >>= 1) {
    if (threadIdx.x < s) red[threadIdx.x] += red[threadIdx.x + s];
    __syncthreads();
  }
  if (threadIdx.x == 0) out[b * 12 + 11] = red[0];
}

// ---------------------------------------------------------------------------
extern "C" void kernel_launch(void* const* d_in, const int* in_sizes, int n_in,
                              void* d_out, int out_size, void* d_ws,
                              size_t ws_size, hipStream_t stream) {
  const int* u = (const int*)d_in[0];
  const int* v = (const int*)d_in[1];
  const int* et = (const int*)d_in[2];
  const int* neg = (const int*)d_in[3];
  const float* time_diff = (const float*)d_in[4];
  const float* t_bar = (const float*)d_in[5];
  const float* t = (const float*)d_in[6];
  const float* z0 = (const float*)d_in[7];
  const float* A = (const float*)d_in[8];
  const float* S = (const float*)d_in[9];
  const float* w_t = (const float*)d_in[10];
  const float* alpha = (const float*)d_in[11];
  const float* psi = (const float*)d_in[12];
  const float* om0_w = (const float*)d_in[13];
  const float* om0_b = (const float*)d_in[14];
  const float* om1_w = (const float*)d_in[15];
  const float* om1_b = (const float*)d_in[16];
  const float* Wh_w = (const float*)d_in[17];
  const float* Wh_b = (const float*)d_in[18];
  const float* Ws_w = (const float*)d_in[19];
  const float* Ws_b = (const float*)d_in[20];
  const float* Wr_w = (const float*)d_in[21];
  const float* Wr_b = (const float*)d_in[22];
  const float* Wt_w = (const float*)d_in[23];
  const float* Wt_b = (const float*)d_in[24];
  float* out = (float*)d_out;

  float* ws = (float*)d_ws;
  float* zws = ws;                       // N*H
  float* whall = zws + (size_t)N * H;    // N*H
  float* WhT = whall + (size_t)N * H;    // H*H
  float* WsT = WhT + H * H;              // H*H
  float* WrT = WsT + H * H;              // H*H
  float* omP = WrT + H * H;              // 4*H
  float* dvec = omP + 4 * H;             // 4*N  [dL0|dR0|dL1|dR1]
  float* lamD = dvec + 4 * N;            // BB*N
  float* su_sv = lamD + (size_t)BB * N;  // 2*BB
  float* qsum = su_sv + 2 * BB;          // 2*BB
  int* cnt = (int*)(qsum + 2 * BB);      // 2*BB
  int* nidx = cnt + 2 * BB;              // 2*BB*MAXN
  float* nes = (float*)(nidx + 2 * BB * MAXN);  // 2*BB*MAXN

  prep_weights_kernel<<<(3 * H * H + 4 * H + 255) / 256, 256, 0, stream>>>(
      Wh_w, Ws_w, Wr_w, om0_w, om1_w, WhT, WsT, WrT, omP);
  copyz_kernel<<<(N * H / 4 + 255) / 256, 256, 0, stream>>>(z0, zws);
  dbase_kernel<<<(N + 255) / 256, 256, 0, stream>>>(z0, om0_w, om1_w, dvec);
  whall_kernel<<<N, H, 0, stream>>>(z0, WhT, Wh_b, whall);
  nbr_kernel<<<2 * BB, 256, 0, stream>>>(u, v, A, S, cnt, nidx, nes, qsum);
  seq_kernel<<<1, 1024, 0, stream>>>(
      u, v, et, neg, time_diff, t_bar, t, omP, om0_b, om1_b, Wh_b, Ws_b, Wr_b,
      Wt_w, Wt_b, w_t, alpha, psi, zws, whall, WhT, WsT, WrT, dvec, lamD,
      su_sv, qsum, cnt, nidx, nes, out);
  lam_kernel<<<BB, 256, 0, stream>>>(u, v, et, t_bar, t, w_t, alpha, psi,
                                     om0_b, om1_b, lamD, su_sv, out);
}

// Round 3
// 1120.932 us; speedup vs baseline: 1.2736x; 1.2736x over previous
//
#include <hip/hip_runtime.h>
#include <math.h>

#define N 8192
#define H 128
#define BB 100
#define KK 5
#define MAXN 256
#define TD_MAXF 10000.0f

// ---------------------------------------------------------------------------
// prep: transpose Wh/Ws/Wr (H x H) to k-major; pack om0_w|om1_w contiguously.
// No pointer selects (if/else chains only) to dodge the gfx950 ISel bug.
__global__ __launch_bounds__(256) void prep_weights_kernel(
    const float* __restrict__ Wh, const float* __restrict__ Ws,
    const float* __restrict__ Wr, const float* __restrict__ om0,
    const float* __restrict__ om1, float* __restrict__ WhT,
    float* __restrict__ WsT, float* __restrict__ WrT, float* __restrict__ omP) {
  int idx = blockIdx.x * 256 + threadIdx.x;
  if (idx < H * H) {
    int d = idx >> 7, k = idx & (H - 1);
    WhT[k * H + d] = Wh[d * H + k];
  } else if (idx < 2 * H * H) {
    int e = idx - H * H;
    int d = e >> 7, k = e & (H - 1);
    WsT[k * H + d] = Ws[d * H + k];
  } else if (idx < 3 * H * H) {
    int e = idx - 2 * H * H;
    int d = e >> 7, k = e & (H - 1);
    WrT[k * H + d] = Wr[d * H + k];
  } else if (idx < 3 * H * H + 2 * H) {
    int e = idx - 3 * H * H;
    omP[e] = om0[e];
  } else if (idx < 3 * H * H + 4 * H) {
    int e = idx - 3 * H * H - 2 * H;
    omP[2 * H + e] = om1[e];
  }
}

// prep: copy z0 -> workspace z (float4)
__global__ __launch_bounds__(256) void copyz_kernel(const float* __restrict__ z0,
                                                    float* __restrict__ zws) {
  int i = blockIdx.x * 256 + threadIdx.x;
  if (i < N * H / 4) ((float4*)zws)[i] = ((const float4*)z0)[i];
}

// prep: base per-node dots with omega halves (from z0).
// dvec0 layout: [dL0 | dR0 | dL1 | dR1], each N floats. PRISTINE (never
// overwritten) -- the scan logs its updates to dlog instead.
__global__ __launch_bounds__(256) void dbase_kernel(
    const float* __restrict__ z0, const float* __restrict__ om0,
    const float* __restrict__ om1, float* __restrict__ dvec0) {
  int j = blockIdx.x * 256 + threadIdx.x;
  if (j >= N) return;
  const float4* zr = (const float4*)(z0 + (size_t)j * H);
  const float4* o0 = (const float4*)om0;
  const float4* o1 = (const float4*)om1;
  float a0 = 0, b0 = 0, a1 = 0, b1 = 0;
  for (int k = 0; k < H / 4; ++k) {
    float4 zv = zr[k];
    float4 l0 = o0[k], r0 = o0[k + H / 4];
    float4 l1 = o1[k], r1 = o1[k + H / 4];
    a0 += zv.x * l0.x + zv.y * l0.y + zv.z * l0.z + zv.w * l0.w;
    b0 += zv.x * r0.x + zv.y * r0.y + zv.z * r0.z + zv.w * r0.w;
    a1 += zv.x * l1.x + zv.y * l1.y + zv.z * l1.z + zv.w * l1.w;
    b1 += zv.x * r1.x + zv.y * r1.y + zv.z * r1.z + zv.w * r1.w;
  }
  dvec0[0 * N + j] = a0;
  dvec0[1 * N + j] = b0;
  dvec0[2 * N + j] = a1;
  dvec0[3 * N + j] = b1;
}

// prep: WhAll = z0 @ Wh.T + Wh_b for all N rows
__global__ __launch_bounds__(128) void whall_kernel(
    const float* __restrict__ z0, const float* __restrict__ WhT,
    const float* __restrict__ Wh_b, float* __restrict__ whall) {
  int n = blockIdx.x;
  __shared__ float zr[H];
  zr[threadIdx.x] = z0[(size_t)n * H + threadIdx.x];
  __syncthreads();
  int d = threadIdx.x;
  float acc = Wh_b[d];
#pragma unroll 8
  for (int k = 0; k < H; ++k) acc += zr[k] * WhT[k * H + d];
  whall[(size_t)n * H + d] = acc;
}

// prep: neighbor lists for the 2B struct() calls. list l = 2*b + r,
// r=0 -> node v[b] (hs row 0), r=1 -> node u[b] (hs row 1).
// Atomic-free: per-thread count -> serial exclusive scan -> deterministic write.
__global__ __launch_bounds__(256) void nbr_kernel(
    const int* __restrict__ u, const int* __restrict__ v,
    const float* __restrict__ A, const float* __restrict__ S,
    int* __restrict__ cnt, int* __restrict__ nidx, float* __restrict__ nes,
    float* __restrict__ qsum) {
  int l = blockIdx.x;
  int b = l >> 1, r = l & 1;
  int node = r ? u[b] : v[b];
  const int tid = threadIdx.x;
  __shared__ int cnts[256];
  __shared__ int excl[257];
  __shared__ float ssum[256];
  int c = 0;
  float local = 0.0f;
  for (int it = 0; it < N / 256; ++it) {
    int j = it * 256 + tid;
    if (A[(size_t)node * N + j] > 0.0f) {
      ++c;
      local += expf(S[(size_t)node * N + j]);
    }
  }
  cnts[tid] = c;
  ssum[tid] = local;
  __syncthreads();
  if (tid == 0) {
    int s = 0;
    for (int i = 0; i < 256; ++i) { excl[i] = s; s += cnts[i]; }
    excl[256] = s;
  }
  __syncthreads();
  int p = excl[tid];
  for (int it = 0; it < N / 256; ++it) {
    int j = it * 256 + tid;
    if (A[(size_t)node * N + j] > 0.0f) {
      if (p < MAXN) {
        nidx[l * MAXN + p] = j;
        nes[l * MAXN + p] = expf(S[(size_t)node * N + j]);
      }
      ++p;
    }
  }
  __syncthreads();
  for (int s = 128; s > 0; s >>= 1) {
    if (tid < s) ssum[tid] += ssum[tid + s];
    __syncthreads();
  }
  if (tid == 0) {
    cnt[l] = min(excl[256], MAXN);
    qsum[l] = ssum[0];
  }
}

// ---------------------------------------------------------------------------
// sequential scan: ONE block, loops b = 0..B-1. Pure recurrence: updates
// zws/whall (global, 2 rows each) and writes an 8-float d-dot log per step.
// All outputs are reconstructed offline from dvec0 + dlog by lam_kernel.
__global__ __launch_bounds__(1024) void seq_kernel(
    const int* __restrict__ u_, const int* __restrict__ v_,
    const int* __restrict__ et_, const float* __restrict__ time_diff,
    const float* __restrict__ omP, const float* __restrict__ Wh_b,
    const float* __restrict__ Ws_b, const float* __restrict__ Wr_b,
    const float* __restrict__ Wt_w, const float* __restrict__ Wt_b,
    float* zws, float* whall, const float* __restrict__ WhT,
    const float* __restrict__ WsT, const float* __restrict__ WrT,
    float* __restrict__ dlog, const float* __restrict__ qsum_,
    const int* __restrict__ cnt_, const int* __restrict__ nidx_,
    const float* __restrict__ nes_) {
  const int t = threadIdx.x;
  // weights resident in LDS (gfx950: 160 KiB/CU)
  __shared__ float wsr[2 * H * H];        // interleaved [k][d][{Ws,Wr}] 128 KB
  __shared__ float scratch[8][2][H];      // smax (as [sub][r][d]) then hpart
  __shared__ float hsS[2][H];
  __shared__ float zrowS[2][H];
  __shared__ float zupdS[2][H];
  __shared__ int nidxS[2][MAXN];
  __shared__ float nqS[2][MAXN];
  __shared__ int uAS[BB], vAS[BB], eAS[BB];
  __shared__ float tdAS[BB * 8];
  __shared__ float biasS[H];   // Ws_b + Wr_b + Wt_b
  __shared__ float Wt4S[H * 4];
  __shared__ float WhbS[H];
  __shared__ float omS[4 * H];
  __shared__ int cntS[2];
  __shared__ float invqS[2];

  // ---- one-time preload --------------------------------------------------
  for (int i = t; i < H * H; i += 1024) {
    wsr[2 * i] = WsT[i];
    wsr[2 * i + 1] = WrT[i];
  }
  if (t < BB) {
    uAS[t] = u_[t];
    vAS[t] = v_[t];
    eAS[t] = et_[t];
  }
  for (int i = t; i < BB * 8; i += 1024) {
    int c = i & 3;
    float sd = (c == 0) ? 50.0f : ((c == 1) ? 7.0f : 15.0f);
    tdAS[i] = time_diff[i] / sd;
  }
  if (t < H) {
    biasS[t] = Ws_b[t] + Wr_b[t] + Wt_b[t];
    WhbS[t] = Wh_b[t];
  }
  if (t < H * 4) Wt4S[t] = Wt_w[t];
  if (t < 4 * H) omS[t] = omP[t];
  __syncthreads();

  for (int b = 0; b < BB; ++b) {
    const int ub = uAS[b], vb = vAS[b];

    // ---- A: stage neighbor lists, z rows, counts -------------------------
    if (t < 512) {
      int r = t >> 8, i = t & 255;
      int l = 2 * b + r;
      nidxS[r][i] = nidx_[l * MAXN + i];
      nqS[r][i] = nes_[l * MAXN + i];
    } else if (t < 768) {
      int t2 = t - 512;
      int r = t2 >> 7, d = t2 & (H - 1);
      int node = r ? vb : ub;
      zrowS[r][d] = zws[(size_t)node * H + d];
    } else if (t == 768) {
      cntS[0] = cnt_[2 * b];
      invqS[0] = 1.0f / (qsum_[2 * b] + 1e-7f);
    } else if (t == 769) {
      cntS[1] = cnt_[2 * b + 1];
      invqS[1] = 1.0f / (qsum_[2 * b + 1] + 1e-7f);
    }
    __syncthreads();

    // ---- B: struct() masked max over neighbors (sigmoid monotone) --------
    {
      int r = t >> 9;
      int sub = (t >> 7) & 3;
      int d = t & (H - 1);
      int c = cntS[r];
      float iq = invqS[r];
      float mx = -INFINITY;
      for (int i = sub; i < c; i += 4) {
        int n = nidxS[r][i];
        mx = fmaxf(mx, nqS[r][i] * iq * whall[(size_t)n * H + d]);
      }
      scratch[sub][r][d] = mx;
    }
    __syncthreads();

    // ---- C: combine -> hs ------------------------------------------------
    if (t < 2 * H) {
      int r = t >> 7, d = t & (H - 1);
      float m = fmaxf(fmaxf(scratch[0][r][d], scratch[1][r][d]),
                      fmaxf(scratch[2][r][d], scratch[3][r][d]));
      hsS[r][d] = (cntS[r] > 0) ? (1.0f / (1.0f + expf(-m))) : 0.0f;
    }
    __syncthreads();

    // ---- D: hpart = hs@Ws.T + zrow@Wr.T (weights from LDS) ---------------
    {
      int ks = t >> 7;
      int d = t & (H - 1);
      int k0 = ks * 16;
      float a0 = 0.0f, a1 = 0.0f;
#pragma unroll 4
      for (int k = k0; k < k0 + 16; ++k) {
        float ws = wsr[2 * (k * H + d)];
        float wr = wsr[2 * (k * H + d) + 1];
        a0 += hsS[0][k] * ws + zrowS[0][k] * wr;
        a1 += hsS[1][k] * ws + zrowS[1][k] * wr;
      }
      scratch[ks][0][d] = a0;
      scratch[ks][1][d] = a1;
    }
    __syncthreads();

    // ---- E: z_upd = sigmoid(h); store z rows (v wins when u==v) ----------
    if (t < 2 * H) {
      int r = t >> 7, d = t & (H - 1);
      float acc = biasS[d];
#pragma unroll
      for (int ks = 0; ks < 8; ++ks) acc += scratch[ks][r][d];
      acc += tdAS[b * 8 + r * 4 + 0] * Wt4S[d * 4 + 0] +
             tdAS[b * 8 + r * 4 + 1] * Wt4S[d * 4 + 1] +
             tdAS[b * 8 + r * 4 + 2] * Wt4S[d * 4 + 2] +
             tdAS[b * 8 + r * 4 + 3] * Wt4S[d * 4 + 3];
      float zu = 1.0f / (1.0f + expf(-acc));
      zupdS[r][d] = zu;
      if (r == 1) {
        zws[(size_t)vb * H + d] = zu;
      } else if (ub != vb) {
        zws[(size_t)ub * H + d] = zu;
      }
    }
    __syncthreads();

    // ---- F: hpart for WhAll rows u,v from NEW z rows ---------------------
    {
      int ks = t >> 7;
      int d = t & (H - 1);
      int k0 = ks * 16;
      int r0 = (ub == vb) ? 1 : 0;  // final z[u] is zupd[1] when u==v
      float a0 = 0.0f, a1 = 0.0f;
#pragma unroll 4
      for (int k = k0; k < k0 + 16; ++k) {
        float wh = WhT[k * H + d];
        a0 += zupdS[r0][k] * wh;
        a1 += zupdS[1][k] * wh;
      }
      scratch[ks][0][d] = a0;
      scratch[ks][1][d] = a1;
    }
    __syncthreads();

    // ---- G: store WhAll rows; log the 8 post-update d-dots ---------------
    if (t < 2 * H) {
      int r = t >> 7, d = t & (H - 1);
      int node = r ? vb : ub;
      float acc = WhbS[d];
#pragma unroll
      for (int ks = 0; ks < 8; ++ks) acc += scratch[ks][r][d];
      whall[(size_t)node * H + d] = acc;
    } else if (t < 768) {
      int w = (t - 256) >> 6;  // 8 waves: (row, which)
      int lane = t & 63;
      int row = w >> 2;
      int which = w & 3;  // 0:dL0 1:dR0 2:dL1 3:dR1
      int rr = (row == 0 && ub == vb) ? 1 : row;
      int wsel = which >> 1;
      int off = (which & 1) * H;
      float val = zupdS[rr][lane] * omS[wsel * 2 * H + off + lane] +
                  zupdS[rr][64 + lane] * omS[wsel * 2 * H + off + 64 + lane];
      for (int s = 32; s > 0; s >>= 1) val += __shfl_down(val, s);
      if (lane == 0) dlog[b * 8 + which * 2 + row] = val;
    }
    __syncthreads();
  }
}

// ---------------------------------------------------------------------------
// offline reconstruction + lam_sum: one block per step b.
// dR_e snapshot rebuilt in LDS from dvec0 + last-writer-filtered dlog replay;
// the 11 hawkes outputs and su/sv come from backward scans over the log.
__global__ __launch_bounds__(256) void lam_kernel(
    const int* __restrict__ u, const int* __restrict__ v,
    const int* __restrict__ etypes, const int* __restrict__ neg_,
    const float* __restrict__ t_bar, const float* __restrict__ tt,
    const float* __restrict__ w_t, const float* __restrict__ alpha,
    const float* __restrict__ psi, const float* __restrict__ om0_b,
    const float* __restrict__ om1_b, const float* __restrict__ dvec0,
    const float* __restrict__ dlog, float* __restrict__ out) {
  const int b = blockIdx.x;
  const int tid = threadIdx.x;
  __shared__ float dR[N];  // 32 KB snapshot of dR_e at step b (pre-update)
  __shared__ int uS[BB], vS[BB];
  __shared__ float red[256];
  __shared__ float suS, svS;

  const int e = etypes[b];
  const int ub = u[b], vb = v[b];
  const float ps = psi[e], al = alpha[e], wt = w_t[e];
  const float ob0 = om0_b[0], ob1 = om1_b[0];
  const float ob = e ? ob1 : ob0;
  const float tcur = tt[b];
  const float inv_ps = 1.0f / (ps + 1e-7f);
  const int whichR = 2 * e + 1;  // dR_e
  const int whichL = 2 * e;      // dL_e

  if (tid < BB) {
    uS[tid] = u[tid];
    vS[tid] = v[tid];
  }
  {
    const float4* base = (const float4*)(dvec0 + (size_t)whichR * N);
    float4* dst = (float4*)dR;
    for (int i = tid; i < N / 4; i += 256) dst[i] = base[i];
  }
  __syncthreads();

  // apply log updates (steps < b), last-writer filtered so writes are unique
  for (int i = tid; i < b; i += 256) {
    int ui = uS[i], vi = vS[i];
    bool u_over = (ui == vi);  // v-write within same step wins
    bool v_over = false;
    for (int j = i + 1; j < b; ++j) {
      int uj = uS[j], vj = vS[j];
      u_over = u_over || (uj == ui) || (vj == ui);
      v_over = v_over || (uj == vi) || (vj == vi);
    }
    if (!u_over) dR[ui] = dlog[i * 8 + whichR * 2 + 0];
    if (!v_over) dR[vi] = dlog[i * 8 + whichR * 2 + 1];
  }

  // hawkes outputs cols 0..10 + su/sv (pre-update values via backward scan)
  if (tid < 13) {
    // pre-update d value of node x for array `which`
    auto dpre = [&](int x, int which) -> float {
      for (int bp = b - 1; bp >= 0; --bp) {
        if (vS[bp] == x) return dlog[bp * 8 + which * 2 + 1];
        if (uS[bp] == x) return dlog[bp * 8 + which * 2 + 0];
      }
      return dvec0[(size_t)which * N + x];
    };
    if (tid < 11) {
      int li, ri;
      float ltu, ltv;
      if (tid == 0) {
        li = ub; ri = vb;
        ltu = t_bar[(size_t)b * N + ub];
        ltv = t_bar[(size_t)b * N + vb];
      } else if (tid <= 5) {
        int vn = neg_[b * (2 * KK) + (tid - 1)];
        li = ub; ri = vn;
        ltu = t_bar[(size_t)b * N + ub];
        ltv = t_bar[(size_t)b * N + vn];
      } else {
        int un = neg_[b * (2 * KK) + (tid - 1)];
        li = un; ri = vb;
        ltu = t_bar[(size_t)b * N + un];
        ltv = t_bar[(size_t)b * N + vb];
      }
      float g = dpre(li, whichL) + dpre(ri, whichR) + ob;
      float gp = fminf(fmaxf(g * inv_ps, -75.0f), 75.0f);
      float ts = tcur - fmaxf(ltu, ltv);
      out[b * 12 + tid] =
          ps * log1pf(expf(gp)) + al * expf(-wt * (ts / TD_MAXF));
    } else if (tid == 11) {
      suS = dpre(ub, whichL);
    } else {
      svS = dpre(vb, whichL);
    }
  }
  __syncthreads();

  const float su = suS, sv = svS;
  const float tb_u = t_bar[(size_t)b * N + ub];
  const float tb_v = t_bar[(size_t)b * N + vb];
  float acc = 0.0f;
  for (int j = tid; j < N; j += 256) {
    if (j == ub || j == vb) continue;
    float d = dR[j];
    float tbj = t_bar[(size_t)b * N + j];
    float gu = su + d + ob;
    float gv = sv + d + ob;
    float gpu_ = fminf(fmaxf(gu * inv_ps, -75.0f), 75.0f);
    float gpv_ = fminf(fmaxf(gv * inv_ps, -75.0f), 75.0f);
    float spl = ps * (log1pf(expf(gpu_)) + log1pf(expf(gpv_)));
    float tdu = tcur - fmaxf(tb_u, tbj);
    float tdv = tcur - fmaxf(tb_v, tbj);
    float ex = al * (expf(-wt * (tdu / TD_MAXF)) + expf(-wt * (tdv / TD_MAXF)));
    acc += spl + ex;
  }
  red[tid] = acc;
  __syncthreads();
  for (int s = 128; s > 0; s >>= 1) {
    if (tid < s) red[tid] += red[tid + s];
    __syncthreads();
  }
  if (tid == 0) out[b * 12 + 11] = red[0];
}

// ---------------------------------------------------------------------------
extern "C" void kernel_launch(void* const* d_in, const int* in_sizes, int n_in,
                              void* d_out, int out_size, void* d_ws,
                              size_t ws_size, hipStream_t stream) {
  const int* u = (const int*)d_in[0];
  const int* v = (const int*)d_in[1];
  const int* et = (const int*)d_in[2];
  const int* neg = (const int*)d_in[3];
  const float* time_diff = (const float*)d_in[4];
  const float* t_bar = (const float*)d_in[5];
  const float* t = (const float*)d_in[6];
  const float* z0 = (const float*)d_in[7];
  const float* A = (const float*)d_in[8];
  const float* S = (const float*)d_in[9];
  const float* w_t = (const float*)d_in[10];
  const float* alpha = (const float*)d_in[11];
  const float* psi = (const float*)d_in[12];
  const float* om0_w = (const float*)d_in[13];
  const float* om0_b = (const float*)d_in[14];
  const float* om1_w = (const float*)d_in[15];
  const float* om1_b = (const float*)d_in[16];
  const float* Wh_w = (const float*)d_in[17];
  const float* Wh_b = (const float*)d_in[18];
  const float* Ws_w = (const float*)d_in[19];
  const float* Ws_b = (const float*)d_in[20];
  const float* Wr_w = (const float*)d_in[21];
  const float* Wr_b = (const float*)d_in[22];
  const float* Wt_w = (const float*)d_in[23];
  const float* Wt_b = (const float*)d_in[24];
  float* out = (float*)d_out;

  float* ws = (float*)d_ws;
  float* zws = ws;                       // N*H
  float* whall = zws + (size_t)N * H;    // N*H
  float* WhT = whall + (size_t)N * H;    // H*H
  float* WsT = WhT + H * H;              // H*H
  float* WrT = WsT + H * H;              // H*H
  float* omP = WrT + H * H;              // 4*H
  float* dvec0 = omP + 4 * H;            // 4*N  [dL0|dR0|dL1|dR1] pristine
  float* dlog = dvec0 + 4 * N;           // 8*BB
  float* qsum = dlog + 8 * BB;           // 2*BB
  int* cnt = (int*)(qsum + 2 * BB);      // 2*BB
  int* nidx = cnt + 2 * BB;              // 2*BB*MAXN
  float* nes = (float*)(nidx + 2 * BB * MAXN);  // 2*BB*MAXN

  prep_weights_kernel<<<(3 * H * H + 4 * H + 255) / 256, 256, 0, stream>>>(
      Wh_w, Ws_w, Wr_w, om0_w, om1_w, WhT, WsT, WrT, omP);
  copyz_kernel<<<(N * H / 4 + 255) / 256, 256, 0, stream>>>(z0, zws);
  dbase_kernel<<<(N + 255) / 256, 256, 0, stream>>>(z0, om0_w, om1_w, dvec0);
  whall_kernel<<<N, H, 0, stream>>>(z0, WhT, Wh_b, whall);
  nbr_kernel<<<2 * BB, 256, 0, stream>>>(u, v, A, S, cnt, nidx, nes, qsum);
  seq_kernel<<<1, 1024, 0, stream>>>(u, v, et, time_diff, omP, Wh_b, Ws_b,
                                     Wr_b, Wt_w, Wt_b, zws, whall, WhT, WsT,
                                     WrT, dlog, qsum, cnt, nidx, nes);
  lam_kernel<<<BB, 256, 0, stream>>>(u, v, et, neg, t_bar, t, w_t, alpha, psi,
                                     om0_b, om1_b, dvec0, dlog, out);
}

// Round 4
// 645.878 us; speedup vs baseline: 2.2103x; 1.7355x over previous
//
#include <hip/hip_runtime.h>
#include <math.h>

#define N 8192
#define H 128
#define BB 100
#define KK 5
#define MAXN 256
#define TD_MAXF 10000.0f

// ws float-offset layout constants (single-base addressing for the gather)
#define OFF_WHALLV ((size_t)N * H)               // versioned whall rows
#define OFF_ZVER (OFF_WHALLV + 2 * BB * H)       // versioned z rows

// ---------------------------------------------------------------------------
// prep: transpose Wh/Ws/Wr (H x H) to k-major; pack om0_w|om1_w; zero flags.
__global__ __launch_bounds__(256) void prep_weights_kernel(
    const float* __restrict__ Wh, const float* __restrict__ Ws,
    const float* __restrict__ Wr, const float* __restrict__ om0,
    const float* __restrict__ om1, float* __restrict__ WhT,
    float* __restrict__ WsT, float* __restrict__ WrT, float* __restrict__ omP,
    unsigned* __restrict__ flags) {
  int idx = blockIdx.x * 256 + threadIdx.x;
  if (idx < H * H) {
    int d = idx >> 7, k = idx & (H - 1);
    WhT[k * H + d] = Wh[d * H + k];
  } else if (idx < 2 * H * H) {
    int e = idx - H * H;
    int d = e >> 7, k = e & (H - 1);
    WsT[k * H + d] = Ws[d * H + k];
  } else if (idx < 3 * H * H) {
    int e = idx - 2 * H * H;
    int d = e >> 7, k = e & (H - 1);
    WrT[k * H + d] = Wr[d * H + k];
  } else if (idx < 3 * H * H + 2 * H) {
    int e = idx - 3 * H * H;
    omP[e] = om0[e];
  } else if (idx < 3 * H * H + 4 * H) {
    int e = idx - 3 * H * H - 2 * H;
    omP[2 * H + e] = om1[e];
  } else if (idx < 3 * H * H + 4 * H + 4 * BB + 4) {
    int e = idx - (3 * H * H + 4 * H);
    flags[e] = 0u;  // need[4*BB] then done[4], contiguous
  }
}

// prep: base per-node dots with omega halves (from z0).
// dvec0 layout: [dL0 | dR0 | dL1 | dR1], each N floats. PRISTINE.
__global__ __launch_bounds__(256) void dbase_kernel(
    const float* __restrict__ z0, const float* __restrict__ om0,
    const float* __restrict__ om1, float* __restrict__ dvec0) {
  int j = blockIdx.x * 256 + threadIdx.x;
  if (j >= N) return;
  const float4* zr = (const float4*)(z0 + (size_t)j * H);
  const float4* o0 = (const float4*)om0;
  const float4* o1 = (const float4*)om1;
  float a0 = 0, b0 = 0, a1 = 0, b1 = 0;
  for (int k = 0; k < H / 4; ++k) {
    float4 zv = zr[k];
    float4 l0 = o0[k], r0 = o0[k + H / 4];
    float4 l1 = o1[k], r1 = o1[k + H / 4];
    a0 += zv.x * l0.x + zv.y * l0.y + zv.z * l0.z + zv.w * l0.w;
    b0 += zv.x * r0.x + zv.y * r0.y + zv.z * r0.z + zv.w * r0.w;
    a1 += zv.x * l1.x + zv.y * l1.y + zv.z * l1.z + zv.w * l1.w;
    b1 += zv.x * r1.x + zv.y * r1.y + zv.z * r1.z + zv.w * r1.w;
  }
  dvec0[0 * N + j] = a0;
  dvec0[1 * N + j] = b0;
  dvec0[2 * N + j] = a1;
  dvec0[3 * N + j] = b1;
}

// prep: base WhAll = z0 @ Wh.T + Wh_b for all N rows (ws offset 0)
__global__ __launch_bounds__(128) void whall_kernel(
    const float* __restrict__ z0, const float* __restrict__ WhT,
    const float* __restrict__ Wh_b, float* __restrict__ whall) {
  int n = blockIdx.x;
  __shared__ float zr[H];
  zr[threadIdx.x] = z0[(size_t)n * H + threadIdx.x];
  __syncthreads();
  int d = threadIdx.x;
  float acc = Wh_b[d];
#pragma unroll 8
  for (int k = 0; k < H; ++k) acc += zr[k] * WhT[k * H + d];
  whall[(size_t)n * H + d] = acc;
}

// prep: neighbor lists for the 2B struct() calls. list l = 2*b + r,
// r=0 -> node v[b] (hs row 0), r=1 -> node u[b] (hs row 1). Atomic-free.
__global__ __launch_bounds__(256) void nbr_kernel(
    const int* __restrict__ u, const int* __restrict__ v,
    const float* __restrict__ A, const float* __restrict__ S,
    int* __restrict__ cnt, int* __restrict__ nidx, float* __restrict__ nes,
    float* __restrict__ qsum) {
  int l = blockIdx.x;
  int b = l >> 1, r = l & 1;
  int node = r ? u[b] : v[b];
  const int tid = threadIdx.x;
  __shared__ int cnts[256];
  __shared__ int excl[257];
  __shared__ float ssum[256];
  int c = 0;
  float local = 0.0f;
  for (int it = 0; it < N / 256; ++it) {
    int j = it * 256 + tid;
    if (A[(size_t)node * N + j] > 0.0f) {
      ++c;
      local += expf(S[(size_t)node * N + j]);
    }
  }
  cnts[tid] = c;
  ssum[tid] = local;
  __syncthreads();
  if (tid == 0) {
    int s = 0;
    for (int i = 0; i < 256; ++i) { excl[i] = s; s += cnts[i]; }
    excl[256] = s;
  }
  __syncthreads();
  int p = excl[tid];
  for (int it = 0; it < N / 256; ++it) {
    int j = it * 256 + tid;
    if (A[(size_t)node * N + j] > 0.0f) {
      if (p < MAXN) {
        nidx[l * MAXN + p] = j;
        nes[l * MAXN + p] = expf(S[(size_t)node * N + j]);
      }
      ++p;
    }
  }
  __syncthreads();
  for (int s = 128; s > 0; s >>= 1) {
    if (tid < s) ssum[tid] += ssum[tid + s];
    __syncthreads();
  }
  if (tid == 0) {
    cnt[l] = min(excl[256], MAXN);
    qsum[l] = ssum[0];
  }
}

// ---------------------------------------------------------------------------
// DAG prep: for each neighbor entry resolve the last-writer step (version) to
// a flat float-offset into ws; build per-step need bitmasks; resolve z-row
// sources. One block per list l = 2*b + r.
__global__ __launch_bounds__(256) void dag_prep_kernel(
    const int* __restrict__ u_, const int* __restrict__ v_,
    const int* __restrict__ cnt_, const int* __restrict__ nidx_,
    int* __restrict__ woff, int* __restrict__ zsrc, unsigned* __restrict__ need) {
  int l = blockIdx.x;
  int b = l >> 1, r = l & 1;
  const int tid = threadIdx.x;
  __shared__ int uL[BB], vL[BB];
  if (tid < BB) {
    uL[tid] = u_[tid];
    vL[tid] = v_[tid];
  }
  __syncthreads();
  int c = cnt_[l];
  for (int i = tid; i < c; i += 256) {
    int n = nidx_[l * MAXN + i];
    int a = -1, row = 0;
    for (int s = b - 1; s >= 0; --s) {
      if (vL[s] == n) { a = s; row = 1; break; }
      if (uL[s] == n) { a = s; row = 0; break; }
    }
    int off;
    if (a < 0) {
      off = n * H;  // base whall at ws offset 0
    } else {
      off = (int)OFF_WHALLV + (2 * a + row) * H;
      atomicOr(&need[b * 4 + (a >> 5)], 1u << (a & 31));
    }
    woff[l * MAXN + i] = off;
  }
  if (r == 0 && tid >= 254) {
    int which = tid - 254;  // 0 -> u_b, 1 -> v_b
    int node = which ? vL[b] : uL[b];
    int a = -1, row = 0;
    for (int s = b - 1; s >= 0; --s) {
      if (vL[s] == node) { a = s; row = 1; break; }
      if (uL[s] == node) { a = s; row = 0; break; }
    }
    int sv = -1;
    if (a >= 0) {
      sv = 2 * a + row;
      atomicOr(&need[b * 4 + (a >> 5)], 1u << (a & 31));
    }
    zsrc[2 * b + which] = sv;
  }
}

// ---------------------------------------------------------------------------
// DAG-parallel scan: one block per step. Spin-waits on producer steps' done
// bits (device-scope atomics + fences, G16), reads versioned state via
// precomputed offsets, writes its own zver/whallv slots + dlog.
__global__ __launch_bounds__(1024) void step_kernel(
    const int* __restrict__ u_, const int* __restrict__ v_,
    const float* __restrict__ time_diff, const float* __restrict__ z0,
    const float* __restrict__ WhT, const float* __restrict__ WsT,
    const float* __restrict__ WrT, const float* __restrict__ omP,
    const float* __restrict__ Wh_b, const float* __restrict__ Ws_b,
    const float* __restrict__ Wr_b, const float* __restrict__ Wt_w,
    const float* __restrict__ Wt_b, const float* __restrict__ wsf,
    float* __restrict__ zver, float* __restrict__ whallv,
    float* __restrict__ dlog, const float* __restrict__ qsum_,
    const int* __restrict__ cnt_, const float* __restrict__ nes_,
    const int* __restrict__ woff_, const int* __restrict__ zsrc_,
    const unsigned* __restrict__ need, unsigned* done) {
  const int b = blockIdx.x;
  const int t = threadIdx.x;
  __shared__ int woffS[2][MAXN];
  __shared__ float nqS[2][MAXN];
  __shared__ float scratch[8][2][H];  // smax [sub][r][d], then hpart [ks][r][d]
  __shared__ float hsS[2][H];
  __shared__ float zrowS[2][H];
  __shared__ float zupdS[2][H];
  __shared__ float td2S[2][4];
  __shared__ int cntS[2], zsrcS[2], uvS[2];
  __shared__ float invqS[2];

  // ---- stage everything that does not depend on other steps --------------
  if (t < 512) {
    int r = t >> 8, i = t & 255;
    int l = 2 * b + r;
    woffS[r][i] = woff_[l * MAXN + i];
    nqS[r][i] = nes_[l * MAXN + i];
  } else if (t < 520) {
    int i = t - 512;
    int c = i & 3;
    float sd = (c == 0) ? 50.0f : ((c == 1) ? 7.0f : 15.0f);
    td2S[i >> 2][c] = time_diff[b * 8 + i] / sd;
  } else if (t < 522) {
    int r = t - 520;
    cntS[r] = cnt_[2 * b + r];
    invqS[r] = 1.0f / (qsum_[2 * b + r] + 1e-7f);
    zsrcS[r] = zsrc_[2 * b + r];
  } else if (t == 522) {
    uvS[0] = u_[b];
  } else if (t == 523) {
    uvS[1] = v_[b];
  }
  // ---- wait for producer steps (device-scope flag + acquire fence) -------
  if (t == 0) {
    for (int w = 0; w < 4; ++w) {
      unsigned nw = need[b * 4 + w];
      while ((atomicOr(&done[w], 0u) & nw) != nw) __builtin_amdgcn_s_sleep(1);
    }
    __threadfence();
  }
  __syncthreads();

  const int ub = uvS[0], vb = uvS[1];

  // ---- B: struct() masked max over neighbors (versioned whall reads);
  //         lanes t<256 also stage z rows afterwards -----------------------
  {
    int r = t >> 9;
    int sub = (t >> 7) & 3;
    int d = t & (H - 1);
    int c = cntS[r];
    float iq = invqS[r];
    float mx = -INFINITY;
#pragma unroll 4
    for (int i = sub; i < c; i += 4)
      mx = fmaxf(mx, nqS[r][i] * iq * wsf[(size_t)woffS[r][i] + d]);
    scratch[sub][r][d] = mx;
  }
  if (t < 256) {
    int r = t >> 7, d = t & (H - 1);
    int s = zsrcS[r];
    int node = r ? vb : ub;
    if (s < 0)
      zrowS[r][d] = z0[(size_t)node * H + d];
    else
      zrowS[r][d] = wsf[OFF_ZVER + (size_t)s * H + d];
  }
  __syncthreads();

  // ---- C: combine -> hs ---------------------------------------------------
  if (t < 2 * H) {
    int r = t >> 7, d = t & (H - 1);
    float m = fmaxf(fmaxf(scratch[0][r][d], scratch[1][r][d]),
                    fmaxf(scratch[2][r][d], scratch[3][r][d]));
    hsS[r][d] = (cntS[r] > 0) ? (1.0f / (1.0f + expf(-m))) : 0.0f;
  }
  __syncthreads();

  // ---- D: hpart = hs@Ws.T + zrow@Wr.T (weights from L2) -------------------
  {
    int ks = t >> 7;
    int d = t & (H - 1);
    int k0 = ks * 16;
    float a0 = 0.0f, a1 = 0.0f;
#pragma unroll 4
    for (int k = k0; k < k0 + 16; ++k) {
      float ws = WsT[k * H + d], wr = WrT[k * H + d];
      a0 += hsS[0][k] * ws + zrowS[0][k] * wr;
      a1 += hsS[1][k] * ws + zrowS[1][k] * wr;
    }
    scratch[ks][0][d] = a0;
    scratch[ks][1][d] = a1;
  }
  __syncthreads();

  // ---- E: z_upd = sigmoid(h); write versioned z rows ----------------------
  if (t < 2 * H) {
    int r = t >> 7, d = t & (H - 1);
    float acc = Ws_b[d] + Wr_b[d] + Wt_b[d];
#pragma unroll
    for (int ks = 0; ks < 8; ++ks) acc += scratch[ks][r][d];
    acc += td2S[r][0] * Wt_w[d * 4 + 0] + td2S[r][1] * Wt_w[d * 4 + 1] +
           td2S[r][2] * Wt_w[d * 4 + 2] + td2S[r][3] * Wt_w[d * 4 + 3];
    float zu = 1.0f / (1.0f + expf(-acc));
    zupdS[r][d] = zu;
    zver[(size_t)(2 * b + r) * H + d] = zu;
  }
  __syncthreads();

  // ---- F: hpart for whall rows u,v from NEW z rows ------------------------
  {
    int ks = t >> 7;
    int d = t & (H - 1);
    int k0 = ks * 16;
    int r0 = (ub == vb) ? 1 : 0;  // final z[u] is zupd[1] when u==v
    float a0 = 0.0f, a1 = 0.0f;
#pragma unroll 4
    for (int k = k0; k < k0 + 16; ++k) {
      float wh = WhT[k * H + d];
      a0 += zupdS[r0][k] * wh;
      a1 += zupdS[1][k] * wh;
    }
    scratch[ks][0][d] = a0;
    scratch[ks][1][d] = a1;
  }
  __syncthreads();

  // ---- G: write versioned whall rows; log the 8 post-update d-dots --------
  if (t < 2 * H) {
    int r = t >> 7, d = t & (H - 1);
    float acc = Wh_b[d];
#pragma unroll
    for (int ks = 0; ks < 8; ++ks) acc += scratch[ks][r][d];
    whallv[(size_t)(2 * b + r) * H + d] = acc;
  } else if (t < 768) {
    int w = (t - 256) >> 6;  // 8 waves: (row, which)
    int lane = t & 63;
    int row = w >> 2;
    int which = w & 3;  // 0:dL0 1:dR0 2:dL1 3:dR1
    int rr = (row == 0 && ub == vb) ? 1 : row;
    int wsel = which >> 1;
    int off = (which & 1) * H;
    float val = zupdS[rr][lane] * omP[wsel * 2 * H + off + lane] +
                zupdS[rr][64 + lane] * omP[wsel * 2 * H + off + 64 + lane];
    for (int s = 32; s > 0; s >>= 1) val += __shfl_down(val, s);
    if (lane == 0) dlog[b * 8 + which * 2 + row] = val;
  }
  __syncthreads();

  // ---- release: publish this step's writes --------------------------------
  if (t == 0) {
    __threadfence();
    atomicOr(&done[b >> 5], 1u << (b & 31));
  }
}

// ---------------------------------------------------------------------------
// offline reconstruction + lam_sum: one block per step b (unchanged).
__global__ __launch_bounds__(256) void lam_kernel(
    const int* __restrict__ u, const int* __restrict__ v,
    const int* __restrict__ etypes, const int* __restrict__ neg_,
    const float* __restrict__ t_bar, const float* __restrict__ tt,
    const float* __restrict__ w_t, const float* __restrict__ alpha,
    const float* __restrict__ psi, const float* __restrict__ om0_b,
    const float* __restrict__ om1_b, const float* __restrict__ dvec0,
    const float* __restrict__ dlog, float* __restrict__ out) {
  const int b = blockIdx.x;
  const int tid = threadIdx.x;
  __shared__ float dR[N];  // 32 KB snapshot of dR_e at step b (pre-update)
  __shared__ int uS[BB], vS[BB];
  __shared__ float red[256];
  __shared__ float suS, svS;

  const int e = etypes[b];
  const int ub = u[b], vb = v[b];
  const float ps = psi[e], al = alpha[e], wt = w_t[e];
  const float ob0 = om0_b[0], ob1 = om1_b[0];
  const float ob = e ? ob1 : ob0;
  const float tcur = tt[b];
  const float inv_ps = 1.0f / (ps + 1e-7f);
  const int whichR = 2 * e + 1;  // dR_e
  const int whichL = 2 * e;      // dL_e

  if (tid < BB) {
    uS[tid] = u[tid];
    vS[tid] = v[tid];
  }
  {
    const float4* base = (const float4*)(dvec0 + (size_t)whichR * N);
    float4* dst = (float4*)dR;
    for (int i = tid; i < N / 4; i += 256) dst[i] = base[i];
  }
  __syncthreads();

  // apply log updates (steps < b), last-writer filtered so writes are unique
  for (int i = tid; i < b; i += 256) {
    int ui = uS[i], vi = vS[i];
    bool u_over = (ui == vi);
    bool v_over = false;
    for (int j = i + 1; j < b; ++j) {
      int uj = uS[j], vj = vS[j];
      u_over = u_over || (uj == ui) || (vj == ui);
      v_over = v_over || (uj == vi) || (vj == vi);
    }
    if (!u_over) dR[ui] = dlog[i * 8 + whichR * 2 + 0];
    if (!v_over) dR[vi] = dlog[i * 8 + whichR * 2 + 1];
  }

  if (tid < 13) {
    auto dpre = [&](int x, int which) -> float {
      for (int bp = b - 1; bp >= 0; --bp) {
        if (vS[bp] == x) return dlog[bp * 8 + which * 2 + 1];
        if (uS[bp] == x) return dlog[bp * 8 + which * 2 + 0];
      }
      return dvec0[(size_t)which * N + x];
    };
    if (tid < 11) {
      int li, ri;
      float ltu, ltv;
      if (tid == 0) {
        li = ub; ri = vb;
        ltu = t_bar[(size_t)b * N + ub];
        ltv = t_bar[(size_t)b * N + vb];
      } else if (tid <= 5) {
        int vn = neg_[b * (2 * KK) + (tid - 1)];
        li = ub; ri = vn;
        ltu = t_bar[(size_t)b * N + ub];
        ltv = t_bar[(size_t)b * N + vn];
      } else {
        int un = neg_[b * (2 * KK) + (tid - 1)];
        li = un; ri = vb;
        ltu = t_bar[(size_t)b * N + un];
        ltv = t_bar[(size_t)b * N + vb];
      }
      float g = dpre(li, whichL) + dpre(ri, whichR) + ob;
      float gp = fminf(fmaxf(g * inv_ps, -75.0f), 75.0f);
      float ts = tcur - fmaxf(ltu, ltv);
      out[b * 12 + tid] =
          ps * log1pf(expf(gp)) + al * expf(-wt * (ts / TD_MAXF));
    } else if (tid == 11) {
      suS = dpre(ub, whichL);
    } else {
      svS = dpre(vb, whichL);
    }
  }
  __syncthreads();

  const float su = suS, sv = svS;
  const float tb_u = t_bar[(size_t)b * N + ub];
  const float tb_v = t_bar[(size_t)b * N + vb];
  float acc = 0.0f;
  for (int j = tid; j < N; j += 256) {
    if (j == ub || j == vb) continue;
    float d = dR[j];
    float tbj = t_bar[(size_t)b * N + j];
    float gu = su + d + ob;
    float gv = sv + d + ob;
    float gpu_ = fminf(fmaxf(gu * inv_ps, -75.0f), 75.0f);
    float gpv_ = fminf(fmaxf(gv * inv_ps, -75.0f), 75.0f);
    float spl = ps * (log1pf(expf(gpu_)) + log1pf(expf(gpv_)));
    float tdu = tcur - fmaxf(tb_u, tbj);
    float tdv = tcur - fmaxf(tb_v, tbj);
    float ex = al * (expf(-wt * (tdu / TD_MAXF)) + expf(-wt * (tdv / TD_MAXF)));
    acc += spl + ex;
  }
  red[tid] = acc;
  __syncthreads();
  for (int s = 128; s > 0; s >>= 1) {
    if (tid < s) red[tid] += red[tid + s];
    __syncthreads();
  }
  if (tid == 0) out[b * 12 + 11] = red[0];
}

// ---------------------------------------------------------------------------
extern "C" void kernel_launch(void* const* d_in, const int* in_sizes, int n_in,
                              void* d_out, int out_size, void* d_ws,
                              size_t ws_size, hipStream_t stream) {
  const int* u = (const int*)d_in[0];
  const int* v = (const int*)d_in[1];
  const int* et = (const int*)d_in[2];
  const int* neg = (const int*)d_in[3];
  const float* time_diff = (const float*)d_in[4];
  const float* t_bar = (const float*)d_in[5];
  const float* t = (const float*)d_in[6];
  const float* z0 = (const float*)d_in[7];
  const float* A = (const float*)d_in[8];
  const float* S = (const float*)d_in[9];
  const float* w_t = (const float*)d_in[10];
  const float* alpha = (const float*)d_in[11];
  const float* psi = (const float*)d_in[12];
  const float* om0_w = (const float*)d_in[13];
  const float* om0_b = (const float*)d_in[14];
  const float* om1_w = (const float*)d_in[15];
  const float* om1_b = (const float*)d_in[16];
  const float* Wh_w = (const float*)d_in[17];
  const float* Wh_b = (const float*)d_in[18];
  const float* Ws_w = (const float*)d_in[19];
  const float* Ws_b = (const float*)d_in[20];
  const float* Wr_w = (const float*)d_in[21];
  const float* Wr_b = (const float*)d_in[22];
  const float* Wt_w = (const float*)d_in[23];
  const float* Wt_b = (const float*)d_in[24];
  float* out = (float*)d_out;

  float* wsf = (float*)d_ws;
  float* whall = wsf;                          // N*H (offset 0)
  float* whallv = wsf + OFF_WHALLV;            // 2*BB*H
  float* zver = wsf + OFF_ZVER;                // 2*BB*H
  float* WhT = zver + 2 * BB * H;              // H*H
  float* WsT = WhT + H * H;                    // H*H
  float* WrT = WsT + H * H;                    // H*H
  float* omP = WrT + H * H;                    // 4*H
  float* dvec0 = omP + 4 * H;                  // 4*N
  float* dlog = dvec0 + 4 * N;                 // 8*BB
  float* qsum = dlog + 8 * BB;                 // 2*BB
  int* cnt = (int*)(qsum + 2 * BB);            // 2*BB
  int* nidx = cnt + 2 * BB;                    // 2*BB*MAXN
  float* nes = (float*)(nidx + 2 * BB * MAXN); // 2*BB*MAXN
  int* woff = (int*)(nes + 2 * BB * MAXN);     // 2*BB*MAXN
  int* zsrc = woff + 2 * BB * MAXN;            // 2*BB
  unsigned* need = (unsigned*)(zsrc + 2 * BB); // 4*BB
  unsigned* done = need + 4 * BB;              // 4 (contiguous after need)

  prep_weights_kernel<<<(3 * H * H + 4 * H + 4 * BB + 4 + 255) / 256, 256, 0,
                        stream>>>(Wh_w, Ws_w, Wr_w, om0_w, om1_w, WhT, WsT,
                                  WrT, omP, need);
  dbase_kernel<<<(N + 255) / 256, 256, 0, stream>>>(z0, om0_w, om1_w, dvec0);
  whall_kernel<<<N, H, 0, stream>>>(z0, WhT, Wh_b, whall);
  nbr_kernel<<<2 * BB, 256, 0, stream>>>(u, v, A, S, cnt, nidx, nes, qsum);
  dag_prep_kernel<<<2 * BB, 256, 0, stream>>>(u, v, cnt, nidx, woff, zsrc,
                                              need);
  step_kernel<<<BB, 1024, 0, stream>>>(
      u, v, time_diff, z0, WhT, WsT, WrT, omP, Wh_b, Ws_b, Wr_b, Wt_w, Wt_b,
      wsf, zver, whallv, dlog, qsum, cnt, nes, woff, zsrc, need, done);
  lam_kernel<<<BB, 256, 0, stream>>>(u, v, et, neg, t_bar, t, w_t, alpha, psi,
                                     om0_b, om1_b, dvec0, dlog, out);
}

// Round 5
// 610.300 us; speedup vs baseline: 2.3391x; 1.0583x over previous
//
#include <hip/hip_runtime.h>
#include <math.h>

#define N 8192
#define H 128
#define BB 100
#define KK 5
#define MAXN 256
#define TD_MAXF 10000.0f

// ws float-offset layout constants (single-base addressing for the gather)
#define OFF_WHALLV ((size_t)N * H)          // versioned whall rows
#define OFF_ZVER (OFF_WHALLV + 2 * BB * H)  // versioned z rows

// ---------------------------------------------------------------------------
// K1: weights transpose + omega pack + flag zero + dbase, by idx range.
__global__ __launch_bounds__(256) void prep_all_kernel(
    const float* __restrict__ Wh, const float* __restrict__ Ws,
    const float* __restrict__ Wr, const float* __restrict__ om0,
    const float* __restrict__ om1, const float* __restrict__ z0,
    float* __restrict__ WhT, float* __restrict__ WsT, float* __restrict__ WrT,
    float* __restrict__ omP, unsigned* __restrict__ flags,
    float* __restrict__ dvec0) {
  const int B0 = H * H, B1 = 2 * H * H, B2 = 3 * H * H;
  const int B3 = B2 + 2 * H, B4 = B2 + 4 * H, B5 = B4 + 4 * BB + 4;
  int idx = blockIdx.x * 256 + threadIdx.x;
  if (idx < B0) {
    int d = idx >> 7, k = idx & (H - 1);
    WhT[k * H + d] = Wh[d * H + k];
  } else if (idx < B1) {
    int e = idx - B0;
    int d = e >> 7, k = e & (H - 1);
    WsT[k * H + d] = Ws[d * H + k];
  } else if (idx < B2) {
    int e = idx - B1;
    int d = e >> 7, k = e & (H - 1);
    WrT[k * H + d] = Wr[d * H + k];
  } else if (idx < B3) {
    int e = idx - B2;
    omP[e] = om0[e];
  } else if (idx < B4) {
    int e = idx - B3;
    omP[2 * H + e] = om1[e];
  } else if (idx < B5) {
    flags[idx - B4] = 0u;  // need[4*BB] then done[4]
  } else if (idx < B5 + N) {
    int j = idx - B5;
    const float4* zr = (const float4*)(z0 + (size_t)j * H);
    const float4* o0 = (const float4*)om0;
    const float4* o1 = (const float4*)om1;
    float a0 = 0, b0 = 0, a1 = 0, b1 = 0;
    for (int k = 0; k < H / 4; ++k) {
      float4 zv = zr[k];
      float4 l0 = o0[k], r0 = o0[k + H / 4];
      float4 l1 = o1[k], r1 = o1[k + H / 4];
      a0 += zv.x * l0.x + zv.y * l0.y + zv.z * l0.z + zv.w * l0.w;
      b0 += zv.x * r0.x + zv.y * r0.y + zv.z * r0.z + zv.w * r0.w;
      a1 += zv.x * l1.x + zv.y * l1.y + zv.z * l1.z + zv.w * l1.w;
      b1 += zv.x * r1.x + zv.y * r1.y + zv.z * r1.z + zv.w * r1.w;
    }
    dvec0[0 * N + j] = a0;
    dvec0[1 * N + j] = b0;
    dvec0[2 * N + j] = a1;
    dvec0[3 * N + j] = b1;
  }
}

// ---------------------------------------------------------------------------
// K2: fused by block range. Blocks [0, N/2): whall (2 rows per block).
// Blocks [N/2, N/2 + 2*BB): nbr list build + DAG resolve for list l.
__global__ __launch_bounds__(256) void build_kernel(
    const float* __restrict__ z0, const float* __restrict__ WhT,
    const float* __restrict__ Wh_b, float* __restrict__ whall,
    const int* __restrict__ u_, const int* __restrict__ v_,
    const float* __restrict__ A, const float* __restrict__ S,
    int* __restrict__ cnt, int* __restrict__ nidx, float* __restrict__ nes,
    float* __restrict__ qsum, int* __restrict__ woff, int* __restrict__ zsrc,
    unsigned* __restrict__ need) {
  const int blk = blockIdx.x;
  const int tid = threadIdx.x;
  __shared__ float zr2[2][H];
  __shared__ int cnts[256];
  __shared__ int excl[257];
  __shared__ float ssum[256];
  __shared__ int nidxL[MAXN];
  __shared__ int uL[BB], vL[BB];

  if (blk < N / 2) {
    // ---- whall: WhAll = z0 @ Wh.T + Wh_b, two rows per block -------------
    int r = tid >> 7, d = tid & (H - 1);
    int row = blk * 2 + r;
    zr2[r][d] = z0[(size_t)row * H + d];
    __syncthreads();
    float acc = Wh_b[d];
#pragma unroll 8
    for (int k = 0; k < H; ++k) acc += zr2[r][k] * WhT[k * H + d];
    whall[(size_t)row * H + d] = acc;
    return;
  }

  // ---- nbr + dag for list l = 2*b + r (r=0 -> v_b, r=1 -> u_b) -----------
  const int l = blk - N / 2;
  const int b = l >> 1, r = l & 1;
  const int node = r ? u_[b] : v_[b];
  int c = 0;
  float local = 0.0f;
  for (int it = 0; it < N / 256; ++it) {
    int j = it * 256 + tid;
    if (A[(size_t)node * N + j] > 0.0f) {
      ++c;
      local += expf(S[(size_t)node * N + j]);
    }
  }
  cnts[tid] = c;
  ssum[tid] = local;
  __syncthreads();
  if (tid == 0) {
    int s = 0;
    for (int i = 0; i < 256; ++i) { excl[i] = s; s += cnts[i]; }
    excl[256] = s;
  }
  __syncthreads();
  int p = excl[tid];
  for (int it = 0; it < N / 256; ++it) {
    int j = it * 256 + tid;
    if (A[(size_t)node * N + j] > 0.0f) {
      if (p < MAXN) {
        nidx[l * MAXN + p] = j;
        nidxL[p] = j;
        nes[l * MAXN + p] = expf(S[(size_t)node * N + j]);
      }
      ++p;
    }
  }
  if (tid < BB) {
    uL[tid] = u_[tid];
    vL[tid] = v_[tid];
  }
  __syncthreads();
  for (int s = 128; s > 0; s >>= 1) {
    if (tid < s) ssum[tid] += ssum[tid + s];
    __syncthreads();
  }
  const int cM = min(excl[256], MAXN);
  if (tid == 0) {
    cnt[l] = cM;
    qsum[l] = ssum[0];
  }
  // dag: resolve last-writer version for each neighbor entry
  for (int i = tid; i < cM; i += 256) {
    int n = nidxL[i];
    int a = -1, row = 0;
    for (int s = b - 1; s >= 0; --s) {
      if (vL[s] == n) { a = s; row = 1; break; }
      if (uL[s] == n) { a = s; row = 0; break; }
    }
    int off;
    if (a < 0) {
      off = n * H;  // base whall at ws offset 0
    } else {
      off = (int)OFF_WHALLV + (2 * a + row) * H;
      atomicOr(&need[b * 4 + (a >> 5)], 1u << (a & 31));
    }
    woff[l * MAXN + i] = off;
  }
  if (r == 0 && tid >= 254) {
    int which = tid - 254;  // 0 -> u_b, 1 -> v_b
    int nd = which ? vL[b] : uL[b];
    int a = -1, row = 0;
    for (int s = b - 1; s >= 0; --s) {
      if (vL[s] == nd) { a = s; row = 1; break; }
      if (uL[s] == nd) { a = s; row = 0; break; }
    }
    int sv = -1;
    if (a >= 0) {
      sv = 2 * a + row;
      atomicOr(&need[b * 4 + (a >> 5)], 1u << (a & 31));
    }
    zsrc[2 * b + which] = sv;
  }
}

// ---------------------------------------------------------------------------
// K3: DAG-parallel scan, one block per step. Base-version gather (B0) runs
// concurrently with t0's producer poll; versioned gather (B1) after acquire.
__global__ __launch_bounds__(1024) void step_kernel(
    const int* __restrict__ u_, const int* __restrict__ v_,
    const float* __restrict__ time_diff, const float* __restrict__ z0,
    const float* __restrict__ WhT, const float* __restrict__ WsT,
    const float* __restrict__ WrT, const float* __restrict__ omP,
    const float* __restrict__ Wh_b, const float* __restrict__ Ws_b,
    const float* __restrict__ Wr_b, const float* __restrict__ Wt_w,
    const float* __restrict__ Wt_b, const float* __restrict__ wsf,
    float* __restrict__ zver, float* __restrict__ whallv,
    float* __restrict__ dlog, const float* __restrict__ qsum_,
    const int* __restrict__ cnt_, const float* __restrict__ nes_,
    const int* __restrict__ woff_, const int* __restrict__ zsrc_,
    const unsigned* __restrict__ need, unsigned* done) {
  const int b = blockIdx.x;
  const int t = threadIdx.x;
  __shared__ float scratch[8][2][H];  // smax [sub][r][d], then hpart [ks][r][d]
  __shared__ float hsS[2][H];
  __shared__ float zrowS[2][H];
  __shared__ float zupdS[2][H];
  __shared__ float td2S[2][4];
  __shared__ int uvS[2];

  const int r = t >> 9;
  const int sub = (t >> 7) & 3;
  const int d = t & (H - 1);
  const int l = 2 * b + r;
  const int c = cnt_[l];
  const float iq = 1.0f / (qsum_[l] + 1e-7f);

  // ---- B0: dependency-free gather (base whall versions) ------------------
  float mx = -INFINITY;
  for (int i = sub; i < c; i += 4) {
    int off = woff_[l * MAXN + i];
    if (off < (int)OFF_WHALLV)
      mx = fmaxf(mx, nes_[l * MAXN + i] * iq * wsf[(size_t)off + d]);
  }
  // pre-wait z-row path (z0 source only)
  float zpre = 0.0f;
  int zs = -1;
  if (t < 256) {
    int rr = t >> 7, dd = t & (H - 1);
    zs = zsrc_[2 * b + rr];
    if (zs < 0) {
      int nd = rr ? v_[b] : u_[b];
      zpre = z0[(size_t)nd * H + dd];
    }
  }
  if (t >= 512 && t < 520) {
    int i = t - 512;
    int cc = i & 3;
    float sd = (cc == 0) ? 50.0f : ((cc == 1) ? 7.0f : 15.0f);
    td2S[i >> 2][cc] = time_diff[b * 8 + i] / sd;
  }
  // ---- poll producers (t0), overlapped with B0 above ---------------------
  if (t == 0) {
    uvS[0] = u_[b];
    uvS[1] = v_[b];
    for (int w = 0; w < 4; ++w) {
      unsigned nw = need[b * 4 + w];
      if (!nw) continue;
      while ((__hip_atomic_load(&done[w], __ATOMIC_RELAXED,
                                __HIP_MEMORY_SCOPE_AGENT) &
              nw) != nw)
        __builtin_amdgcn_s_sleep(1);
    }
    __threadfence();  // acquire
  }
  __syncthreads();

  const int ub = uvS[0], vb = uvS[1];

  // ---- B1: versioned gather + versioned z rows ---------------------------
  for (int i = sub; i < c; i += 4) {
    int off = woff_[l * MAXN + i];
    if (off >= (int)OFF_WHALLV)
      mx = fmaxf(mx, nes_[l * MAXN + i] * iq * wsf[(size_t)off + d]);
  }
  scratch[sub][r][d] = mx;
  if (t < 256) {
    int rr = t >> 7, dd = t & (H - 1);
    float zv;
    if (zs < 0)
      zv = zpre;
    else
      zv = wsf[OFF_ZVER + (size_t)zs * H + dd];
    zrowS[rr][dd] = zv;
  }
  __syncthreads();

  // ---- C: combine -> hs --------------------------------------------------
  if (t < 2 * H) {
    int rr = t >> 7, dd = t & (H - 1);
    float m = fmaxf(fmaxf(scratch[0][rr][dd], scratch[1][rr][dd]),
                    fmaxf(scratch[2][rr][dd], scratch[3][rr][dd]));
    hsS[rr][dd] = (c > 0 || rr != r || true)
                      ? ((cnt_[2 * b + rr] > 0)
                             ? (1.0f / (1.0f + expf(-m)))
                             : 0.0f)
                      : 0.0f;
  }
  __syncthreads();

  // ---- D: hpart = hs@Ws.T + zrow@Wr.T ------------------------------------
  {
    int ks = t >> 7;
    int k0 = ks * 16;
    float a0 = 0.0f, a1 = 0.0f;
#pragma unroll 4
    for (int k = k0; k < k0 + 16; ++k) {
      float ws = WsT[k * H + d], wr = WrT[k * H + d];
      a0 += hsS[0][k] * ws + zrowS[0][k] * wr;
      a1 += hsS[1][k] * ws + zrowS[1][k] * wr;
    }
    scratch[ks][0][d] = a0;
    scratch[ks][1][d] = a1;
  }
  __syncthreads();

  // ---- E: z_upd = sigmoid(h); write versioned z rows ---------------------
  if (t < 2 * H) {
    int rr = t >> 7, dd = t & (H - 1);
    float acc = Ws_b[dd] + Wr_b[dd] + Wt_b[dd];
#pragma unroll
    for (int ks = 0; ks < 8; ++ks) acc += scratch[ks][rr][dd];
    acc += td2S[rr][0] * Wt_w[dd * 4 + 0] + td2S[rr][1] * Wt_w[dd * 4 + 1] +
           td2S[rr][2] * Wt_w[dd * 4 + 2] + td2S[rr][3] * Wt_w[dd * 4 + 3];
    float zu = 1.0f / (1.0f + expf(-acc));
    zupdS[rr][dd] = zu;
    zver[(size_t)(2 * b + rr) * H + dd] = zu;
  }
  __syncthreads();

  // ---- F: hpart for whall rows u,v from NEW z rows -----------------------
  {
    int ks = t >> 7;
    int k0 = ks * 16;
    int r0 = (ub == vb) ? 1 : 0;  // final z[u] is zupd[1] when u==v
    float a0 = 0.0f, a1 = 0.0f;
#pragma unroll 4
    for (int k = k0; k < k0 + 16; ++k) {
      float wh = WhT[k * H + d];
      a0 += zupdS[r0][k] * wh;
      a1 += zupdS[1][k] * wh;
    }
    scratch[ks][0][d] = a0;
    scratch[ks][1][d] = a1;
  }
  __syncthreads();

  // ---- G: whallv store (t<256) || dlog wave-reductions (t in [256,768)) --
  if (t < 2 * H) {
    int rr = t >> 7, dd = t & (H - 1);
    float acc = Wh_b[dd];
#pragma unroll
    for (int ks = 0; ks < 8; ++ks) acc += scratch[ks][rr][dd];
    whallv[(size_t)(2 * b + rr) * H + dd] = acc;
  } else if (t < 768) {
    int w = (t - 256) >> 6;  // 8 waves: (row, which)
    int lane = t & 63;
    int row = w >> 2;
    int which = w & 3;  // 0:dL0 1:dR0 2:dL1 3:dR1
    int rr = (row == 0 && ub == vb) ? 1 : row;
    int wsel = which >> 1;
    int off = (which & 1) * H;
    float val = zupdS[rr][lane] * omP[wsel * 2 * H + off + lane] +
                zupdS[rr][64 + lane] * omP[wsel * 2 * H + off + 64 + lane];
    for (int s = 32; s > 0; s >>= 1) val += __shfl_down(val, s);
    if (lane == 0) dlog[b * 8 + which * 2 + row] = val;
  }
  __syncthreads();

  // ---- release: publish this step's writes -------------------------------
  if (t == 0) {
    __threadfence();
    atomicOr(&done[b >> 5], 1u << (b & 31));
  }
}

// ---------------------------------------------------------------------------
// K4: offline reconstruction + lam_sum, one block per step b, 1024 threads.
__global__ __launch_bounds__(1024) void lam_kernel(
    const int* __restrict__ u, const int* __restrict__ v,
    const int* __restrict__ etypes, const int* __restrict__ neg_,
    const float* __restrict__ t_bar, const float* __restrict__ tt,
    const float* __restrict__ w_t, const float* __restrict__ alpha,
    const float* __restrict__ psi, const float* __restrict__ om0_b,
    const float* __restrict__ om1_b, const float* __restrict__ dvec0,
    const float* __restrict__ dlog, float* __restrict__ out) {
  const int b = blockIdx.x;
  const int tid = threadIdx.x;
  __shared__ float dR[N];  // 32 KB snapshot of dR_e at step b (pre-update)
  __shared__ int uS[BB], vS[BB];
  __shared__ float red[1024];
  __shared__ float suS, svS;

  const int e = etypes[b];
  const int ub = u[b], vb = v[b];
  const float ps = psi[e], al = alpha[e], wt = w_t[e];
  const float ob0 = om0_b[0], ob1 = om1_b[0];
  const float ob = e ? ob1 : ob0;
  const float tcur = tt[b];
  const float inv_ps = 1.0f / (ps + 1e-7f);
  const int whichR = 2 * e + 1;  // dR_e
  const int whichL = 2 * e;      // dL_e

  if (tid < BB) {
    uS[tid] = u[tid];
    vS[tid] = v[tid];
  }
  {
    const float4* base = (const float4*)(dvec0 + (size_t)whichR * N);
    float4* dst = (float4*)dR;
    for (int i = tid; i < N / 4; i += 1024) dst[i] = base[i];
  }
  __syncthreads();

  // apply log updates (steps < b), last-writer filtered so writes are unique
  for (int i = tid; i < b; i += 1024) {
    int ui = uS[i], vi = vS[i];
    bool u_over = (ui == vi);
    bool v_over = false;
    for (int j = i + 1; j < b; ++j) {
      int uj = uS[j], vj = vS[j];
      u_over = u_over || (uj == ui) || (vj == ui);
      v_over = v_over || (uj == vi) || (vj == vi);
    }
    if (!u_over) dR[ui] = dlog[i * 8 + whichR * 2 + 0];
    if (!v_over) dR[vi] = dlog[i * 8 + whichR * 2 + 1];
  }

  if (tid < 13) {
    auto dpre = [&](int x, int which) -> float {
      for (int bp = b - 1; bp >= 0; --bp) {
        if (vS[bp] == x) return dlog[bp * 8 + which * 2 + 1];
        if (uS[bp] == x) return dlog[bp * 8 + which * 2 + 0];
      }
      return dvec0[(size_t)which * N + x];
    };
    if (tid < 11) {
      int li, ri;
      float ltu, ltv;
      if (tid == 0) {
        li = ub; ri = vb;
        ltu = t_bar[(size_t)b * N + ub];
        ltv = t_bar[(size_t)b * N + vb];
      } else if (tid <= 5) {
        int vn = neg_[b * (2 * KK) + (tid - 1)];
        li = ub; ri = vn;
        ltu = t_bar[(size_t)b * N + ub];
        ltv = t_bar[(size_t)b * N + vn];
      } else {
        int un = neg_[b * (2 * KK) + (tid - 1)];
        li = un; ri = vb;
        ltu = t_bar[(size_t)b * N + un];
        ltv = t_bar[(size_t)b * N + vb];
      }
      float g = dpre(li, whichL) + dpre(ri, whichR) + ob;
      float gp = fminf(fmaxf(g * inv_ps, -75.0f), 75.0f);
      float ts = tcur - fmaxf(ltu, ltv);
      out[b * 12 + tid] =
          ps * log1pf(expf(gp)) + al * expf(-wt * (ts / TD_MAXF));
    } else if (tid == 11) {
      suS = dpre(ub, whichL);
    } else {
      svS = dpre(vb, whichL);
    }
  }
  __syncthreads();

  const float su = suS, sv = svS;
  const float tb_u = t_bar[(size_t)b * N + ub];
  const float tb_v = t_bar[(size_t)b * N + vb];
  const float4* tb4 = (const float4*)(t_bar + (size_t)b * N);
  const float4* dR4 = (const float4*)dR;
  float acc = 0.0f;
  for (int j4 = tid; j4 < N / 4; j4 += 1024) {
    float4 dv = dR4[j4];
    float4 tb = tb4[j4];
    float de[4] = {dv.x, dv.y, dv.z, dv.w};
    float te[4] = {tb.x, tb.y, tb.z, tb.w};
#pragma unroll
    for (int ee = 0; ee < 4; ++ee) {
      int j = j4 * 4 + ee;
      if (j == ub || j == vb) continue;
      float dd = de[ee];
      float tbj = te[ee];
      float gu = su + dd + ob;
      float gv = sv + dd + ob;
      float gpu_ = fminf(fmaxf(gu * inv_ps, -75.0f), 75.0f);
      float gpv_ = fminf(fmaxf(gv * inv_ps, -75.0f), 75.0f);
      float spl = ps * (log1pf(expf(gpu_)) + log1pf(expf(gpv_)));
      float tdu = tcur - fmaxf(tb_u, tbj);
      float tdv = tcur - fmaxf(tb_v, tbj);
      float ex =
          al * (expf(-wt * (tdu / TD_MAXF)) + expf(-wt * (tdv / TD_MAXF)));
      acc += spl + ex;
    }
  }
  red[tid] = acc;
  __syncthreads();
  for (int s = 512; s > 0; s >>= 1) {
    if (tid < s) red[tid] += red[tid + s];
    __syncthreads();
  }
  if (tid == 0) out[b * 12 + 11] = red[0];
}

// ---------------------------------------------------------------------------
extern "C" void kernel_launch(void* const* d_in, const int* in_sizes, int n_in,
                              void* d_out, int out_size, void* d_ws,
                              size_t ws_size, hipStream_t stream) {
  const int* u = (const int*)d_in[0];
  const int* v = (const int*)d_in[1];
  const int* et = (const int*)d_in[2];
  const int* neg = (const int*)d_in[3];
  const float* time_diff = (const float*)d_in[4];
  const float* t_bar = (const float*)d_in[5];
  const float* t = (const float*)d_in[6];
  const float* z0 = (const float*)d_in[7];
  const float* A = (const float*)d_in[8];
  const float* S = (const float*)d_in[9];
  const float* w_t = (const float*)d_in[10];
  const float* alpha = (const float*)d_in[11];
  const float* psi = (const float*)d_in[12];
  const float* om0_w = (const float*)d_in[13];
  const float* om0_b = (const float*)d_in[14];
  const float* om1_w = (const float*)d_in[15];
  const float* om1_b = (const float*)d_in[16];
  const float* Wh_w = (const float*)d_in[17];
  const float* Wh_b = (const float*)d_in[18];
  const float* Ws_w = (const float*)d_in[19];
  const float* Ws_b = (const float*)d_in[20];
  const float* Wr_w = (const float*)d_in[21];
  const float* Wr_b = (const float*)d_in[22];
  const float* Wt_w = (const float*)d_in[23];
  const float* Wt_b = (const float*)d_in[24];
  float* out = (float*)d_out;

  float* wsf = (float*)d_ws;
  float* whall = wsf;                           // N*H (offset 0)
  float* whallv = wsf + OFF_WHALLV;             // 2*BB*H
  float* zver = wsf + OFF_ZVER;                 // 2*BB*H
  float* WhT = zver + 2 * BB * H;               // H*H
  float* WsT = WhT + H * H;                     // H*H
  float* WrT = WsT + H * H;                     // H*H
  float* omP = WrT + H * H;                     // 4*H
  float* dvec0 = omP + 4 * H;                   // 4*N
  float* dlog = dvec0 + 4 * N;                  // 8*BB
  float* qsum = dlog + 8 * BB;                  // 2*BB
  int* cnt = (int*)(qsum + 2 * BB);             // 2*BB
  int* nidx = cnt + 2 * BB;                     // 2*BB*MAXN
  float* nes = (float*)(nidx + 2 * BB * MAXN);  // 2*BB*MAXN
  int* woff = (int*)(nes + 2 * BB * MAXN);      // 2*BB*MAXN
  int* zsrc = woff + 2 * BB * MAXN;             // 2*BB
  unsigned* need = (unsigned*)(zsrc + 2 * BB);  // 4*BB
  unsigned* done = need + 4 * BB;               // 4 (contiguous after need)

  const int PREP_ELEMS = 3 * H * H + 4 * H + 4 * BB + 4 + N;
  prep_all_kernel<<<(PREP_ELEMS + 255) / 256, 256, 0, stream>>>(
      Wh_w, Ws_w, Wr_w, om0_w, om1_w, z0, WhT, WsT, WrT, omP, need, dvec0);
  build_kernel<<<N / 2 + 2 * BB, 256, 0, stream>>>(
      z0, WhT, Wh_b, whall, u, v, A, S, cnt, nidx, nes, qsum, woff, zsrc,
      need);
  step_kernel<<<BB, 1024, 0, stream>>>(
      u, v, time_diff, z0, WhT, WsT, WrT, omP, Wh_b, Ws_b, Wr_b, Wt_w, Wt_b,
      wsf, zver, whallv, dlog, qsum, cnt, nes, woff, zsrc, need, done);
  lam_kernel<<<BB, 1024, 0, stream>>>(u, v, et, neg, t_bar, t, w_t, alpha, psi,
                                      om0_b, om1_b, dvec0, dlog, out);
}

// Round 6
// 606.108 us; speedup vs baseline: 2.3553x; 1.0069x over previous
//
#include <hip/hip_runtime.h>
#include <math.h>

#define N 8192
#define H 128
#define BB 100
#define KK 5
#define MAXN 256
#define TD_MAXF 10000.0f

// ws float-offset layout constants (single-base addressing for the gather)
#define OFF_WHALLV ((size_t)N * H)          // versioned whall rows
#define OFF_ZVER (OFF_WHALLV + 2 * BB * H)  // versioned z rows

// ---------------------------------------------------------------------------
// K1: weights transpose + omega pack + flag zero + dbase, by idx range.
__global__ __launch_bounds__(256) void prep_all_kernel(
    const float* __restrict__ Wh, const float* __restrict__ Ws,
    const float* __restrict__ Wr, const float* __restrict__ om0,
    const float* __restrict__ om1, const float* __restrict__ z0,
    float* __restrict__ WhT, float* __restrict__ WsT, float* __restrict__ WrT,
    float* __restrict__ omP, unsigned* __restrict__ flags,
    float* __restrict__ dvec0) {
  const int B0 = H * H, B1 = 2 * H * H, B2 = 3 * H * H;
  const int B3 = B2 + 2 * H, B4 = B2 + 4 * H, B5 = B4 + 4 * BB + 4;
  int idx = blockIdx.x * 256 + threadIdx.x;
  if (idx < B0) {
    int d = idx >> 7, k = idx & (H - 1);
    WhT[k * H + d] = Wh[d * H + k];
  } else if (idx < B1) {
    int e = idx - B0;
    int d = e >> 7, k = e & (H - 1);
    WsT[k * H + d] = Ws[d * H + k];
  } else if (idx < B2) {
    int e = idx - B1;
    int d = e >> 7, k = e & (H - 1);
    WrT[k * H + d] = Wr[d * H + k];
  } else if (idx < B3) {
    int e = idx - B2;
    omP[e] = om0[e];
  } else if (idx < B4) {
    int e = idx - B3;
    omP[2 * H + e] = om1[e];
  } else if (idx < B5) {
    flags[idx - B4] = 0u;  // need[4*BB] then done[4]
  } else if (idx < B5 + N) {
    int j = idx - B5;
    const float4* zr = (const float4*)(z0 + (size_t)j * H);
    const float4* o0 = (const float4*)om0;
    const float4* o1 = (const float4*)om1;
    float a0 = 0, b0 = 0, a1 = 0, b1 = 0;
    for (int k = 0; k < H / 4; ++k) {
      float4 zv = zr[k];
      float4 l0 = o0[k], r0 = o0[k + H / 4];
      float4 l1 = o1[k], r1 = o1[k + H / 4];
      a0 += zv.x * l0.x + zv.y * l0.y + zv.z * l0.z + zv.w * l0.w;
      b0 += zv.x * r0.x + zv.y * r0.y + zv.z * r0.z + zv.w * r0.w;
      a1 += zv.x * l1.x + zv.y * l1.y + zv.z * l1.z + zv.w * l1.w;
      b1 += zv.x * r1.x + zv.y * r1.y + zv.z * r1.z + zv.w * r1.w;
    }
    dvec0[0 * N + j] = a0;
    dvec0[1 * N + j] = b0;
    dvec0[2 * N + j] = a1;
    dvec0[3 * N + j] = b1;
  }
}

// ---------------------------------------------------------------------------
// K2: fused by block range. Blocks [0, N/2): whall (2 rows per block).
// Blocks [N/2, N/2 + 2*BB): nbr list build + DAG resolve for list l.
__global__ __launch_bounds__(256) void build_kernel(
    const float* __restrict__ z0, const float* __restrict__ WhT,
    const float* __restrict__ Wh_b, float* __restrict__ whall,
    const int* __restrict__ u_, const int* __restrict__ v_,
    const float* __restrict__ A, const float* __restrict__ S,
    int* __restrict__ cnt, int* __restrict__ nidx, float* __restrict__ nes,
    float* __restrict__ qsum, int* __restrict__ woff, int* __restrict__ zsrc,
    unsigned* __restrict__ need) {
  const int blk = blockIdx.x;
  const int tid = threadIdx.x;
  __shared__ float zr2[2][H];
  __shared__ int cnts[256];
  __shared__ int excl[257];
  __shared__ float ssum[256];
  __shared__ int nidxL[MAXN];
  __shared__ int uL[BB], vL[BB];

  if (blk < N / 2) {
    int r = tid >> 7, d = tid & (H - 1);
    int row = blk * 2 + r;
    zr2[r][d] = z0[(size_t)row * H + d];
    __syncthreads();
    float acc = Wh_b[d];
#pragma unroll 8
    for (int k = 0; k < H; ++k) acc += zr2[r][k] * WhT[k * H + d];
    whall[(size_t)row * H + d] = acc;
    return;
  }

  const int l = blk - N / 2;
  const int b = l >> 1, r = l & 1;
  const int node = r ? u_[b] : v_[b];
  int c = 0;
  float local = 0.0f;
  for (int it = 0; it < N / 256; ++it) {
    int j = it * 256 + tid;
    if (A[(size_t)node * N + j] > 0.0f) {
      ++c;
      local += expf(S[(size_t)node * N + j]);
    }
  }
  cnts[tid] = c;
  ssum[tid] = local;
  __syncthreads();
  if (tid == 0) {
    int s = 0;
    for (int i = 0; i < 256; ++i) { excl[i] = s; s += cnts[i]; }
    excl[256] = s;
  }
  __syncthreads();
  int p = excl[tid];
  for (int it = 0; it < N / 256; ++it) {
    int j = it * 256 + tid;
    if (A[(size_t)node * N + j] > 0.0f) {
      if (p < MAXN) {
        nidx[l * MAXN + p] = j;
        nidxL[p] = j;
        nes[l * MAXN + p] = expf(S[(size_t)node * N + j]);
      }
      ++p;
    }
  }
  if (tid < BB) {
    uL[tid] = u_[tid];
    vL[tid] = v_[tid];
  }
  __syncthreads();
  for (int s = 128; s > 0; s >>= 1) {
    if (tid < s) ssum[tid] += ssum[tid + s];
    __syncthreads();
  }
  const int cM = min(excl[256], MAXN);
  if (tid == 0) {
    cnt[l] = cM;
    qsum[l] = ssum[0];
  }
  for (int i = tid; i < cM; i += 256) {
    int n = nidxL[i];
    int a = -1, row = 0;
    for (int s = b - 1; s >= 0; --s) {
      if (vL[s] == n) { a = s; row = 1; break; }
      if (uL[s] == n) { a = s; row = 0; break; }
    }
    int off;
    if (a < 0) {
      off = n * H;
    } else {
      off = (int)OFF_WHALLV + (2 * a + row) * H;
      atomicOr(&need[b * 4 + (a >> 5)], 1u << (a & 31));
    }
    woff[l * MAXN + i] = off;
  }
  if (r == 0 && tid >= 254) {
    int which = tid - 254;  // 0 -> u_b, 1 -> v_b
    int nd = which ? vL[b] : uL[b];
    int a = -1, row = 0;
    for (int s = b - 1; s >= 0; --s) {
      if (vL[s] == nd) { a = s; row = 1; break; }
      if (uL[s] == nd) { a = s; row = 0; break; }
    }
    int sv = -1;
    if (a >= 0) {
      sv = 2 * a + row;
      atomicOr(&need[b * 4 + (a >> 5)], 1u << (a & 31));
    }
    zsrc[2 * b + which] = sv;
  }
}

// ---------------------------------------------------------------------------
// K3 fused: blocks [0,BB) = DAG-parallel step; blocks [BB,2BB) = lam for
// step blk-BB (polls the same done bits; needs only steps < b).
__global__ __launch_bounds__(1024) void fused_kernel(
    const int* __restrict__ u_, const int* __restrict__ v_,
    const int* __restrict__ et_, const int* __restrict__ neg_,
    const float* __restrict__ time_diff, const float* __restrict__ t_bar,
    const float* __restrict__ tt, const float* __restrict__ z0,
    const float* __restrict__ WhT, const float* __restrict__ WsT,
    const float* __restrict__ WrT, const float* __restrict__ omP,
    const float* __restrict__ Wh_b, const float* __restrict__ Ws_b,
    const float* __restrict__ Wr_b, const float* __restrict__ Wt_w,
    const float* __restrict__ Wt_b, const float* __restrict__ w_t,
    const float* __restrict__ alpha, const float* __restrict__ psi,
    const float* __restrict__ om0_b, const float* __restrict__ om1_b,
    const float* __restrict__ wsf, float* __restrict__ zver,
    float* __restrict__ whallv, float* __restrict__ dlog,
    const float* __restrict__ qsum_, const int* __restrict__ cnt_,
    const float* __restrict__ nes_, const int* __restrict__ woff_,
    const int* __restrict__ zsrc_, const float* __restrict__ dvec0,
    const unsigned* __restrict__ need, unsigned* done,
    float* __restrict__ out) {
  const int blk = blockIdx.x;
  const int t = threadIdx.x;
  // step-part LDS
  __shared__ float scratch[8][2][H];
  __shared__ float hsS[2][H];
  __shared__ float zrowS[2][H];
  __shared__ float zupdS[2][H];
  __shared__ float td2S[2][4];
  __shared__ int woffS[2][MAXN];
  __shared__ float nqS[2][MAXN];
  __shared__ int cntS[2];
  __shared__ int uvS[2];
  // lam-part LDS
  __shared__ float dR[N];  // 32 KB
  __shared__ int uS[BB], vS[BB];
  __shared__ float red[1024];
  __shared__ float suS, svS;

  if (blk < BB) {
    // =============================== STEP ================================
    const int b = blk;
    const int r = t >> 9;
    const int sub = (t >> 7) & 3;
    const int d = t & (H - 1);
    const int l = 2 * b + r;
    const int c = cnt_[l];
    const float iq = 1.0f / (qsum_[l] + 1e-7f);
    const int ks = t >> 7;
    const int k0 = ks * 16;

    // ---- pre-poll staging (LDS) ----
    if (t < 512) {
      int rr = t >> 8, i = t & 255;
      woffS[rr][i] = woff_[(2 * b + rr) * MAXN + i];
      nqS[rr][i] = nes_[(2 * b + rr) * MAXN + i];
    } else if (t < 520) {
      int i = t - 512;
      int cc = i & 3;
      float sd = (cc == 0) ? 50.0f : ((cc == 1) ? 7.0f : 15.0f);
      td2S[i >> 2][cc] = time_diff[b * 8 + i] / sd;
    } else if (t < 522) {
      cntS[t - 520] = cnt_[2 * b + (t - 520)];
    } else if (t == 522) {
      uvS[0] = u_[b];
    } else if (t == 523) {
      uvS[1] = v_[b];
    }
    // ---- pre-poll register prefetch (kills post-poll L2 latency) ----
    float wsReg[16], wrReg[16], whReg[16];
#pragma unroll
    for (int kk = 0; kk < 16; ++kk) {
      wsReg[kk] = WsT[(k0 + kk) * H + d];
      wrReg[kk] = WrT[(k0 + kk) * H + d];
      whReg[kk] = WhT[(k0 + kk) * H + d];
    }
    float biasReg = 0.0f, whbReg = 0.0f;
    float4 wt4Reg = {0.0f, 0.0f, 0.0f, 0.0f};
    float zpre = 0.0f;
    int zs = -1;
    if (t < 256) {
      int dd = t & (H - 1);
      biasReg = Ws_b[dd] + Wr_b[dd] + Wt_b[dd];
      whbReg = Wh_b[dd];
      wt4Reg = ((const float4*)Wt_w)[dd];
      int rr = t >> 7;
      zs = zsrc_[2 * b + rr];
      if (zs < 0) {
        int nd = rr ? v_[b] : u_[b];
        zpre = z0[(size_t)nd * H + dd];
      }
    }
    float omA = 0.0f, omB = 0.0f;
    if (t >= 256 && t < 768) {
      int w = (t - 256) >> 6;
      int lane = t & 63;
      int which = w & 3;
      int wsel = which >> 1;
      int offo = (which & 1) * H;
      omA = omP[wsel * 2 * H + offo + lane];
      omB = omP[wsel * 2 * H + offo + 64 + lane];
    }
    __syncthreads();  // staging visible

    // ---- B0: dependency-free gather (base whall versions) ----
    float mx = -INFINITY;
    for (int i = sub; i < c; i += 4) {
      int off = woffS[r][i];
      if (off < (int)OFF_WHALLV)
        mx = fmaxf(mx, nqS[r][i] * iq * wsf[(size_t)off + d]);
    }
    // ---- poll producers (t0), overlapped with B0 ----
    if (t == 0) {
      for (int w = 0; w < 4; ++w) {
        unsigned nw = need[b * 4 + w];
        if (!nw) continue;
        while ((__hip_atomic_load(&done[w], __ATOMIC_RELAXED,
                                  __HIP_MEMORY_SCOPE_AGENT) &
                nw) != nw)
          __builtin_amdgcn_s_sleep(1);
      }
      __threadfence();  // acquire
    }
    __syncthreads();

    const int ub = uvS[0], vb = uvS[1];

    // ---- B1: versioned gather + versioned z rows ----
    for (int i = sub; i < c; i += 4) {
      int off = woffS[r][i];
      if (off >= (int)OFF_WHALLV)
        mx = fmaxf(mx, nqS[r][i] * iq * wsf[(size_t)off + d]);
    }
    scratch[sub][r][d] = mx;
    if (t < 256) {
      int rr = t >> 7, dd = t & (H - 1);
      zrowS[rr][dd] = (zs < 0) ? zpre : wsf[OFF_ZVER + (size_t)zs * H + dd];
    }
    __syncthreads();

    // ---- C: combine -> hs ----
    if (t < 2 * H) {
      int rr = t >> 7, dd = t & (H - 1);
      float m = fmaxf(fmaxf(scratch[0][rr][dd], scratch[1][rr][dd]),
                      fmaxf(scratch[2][rr][dd], scratch[3][rr][dd]));
      hsS[rr][dd] = (cntS[rr] > 0) ? (1.0f / (1.0f + expf(-m))) : 0.0f;
    }
    __syncthreads();

    // ---- D: hpart = hs@Ws.T + zrow@Wr.T (registers) ----
    {
      float a0 = 0.0f, a1 = 0.0f;
#pragma unroll
      for (int kk = 0; kk < 16; ++kk) {
        int k = k0 + kk;
        a0 += hsS[0][k] * wsReg[kk] + zrowS[0][k] * wrReg[kk];
        a1 += hsS[1][k] * wsReg[kk] + zrowS[1][k] * wrReg[kk];
      }
      scratch[ks][0][d] = a0;
      scratch[ks][1][d] = a1;
    }
    __syncthreads();

    // ---- E: z_upd = sigmoid(h); write versioned z rows ----
    if (t < 2 * H) {
      int rr = t >> 7, dd = t & (H - 1);
      float acc = biasReg;
#pragma unroll
      for (int kx = 0; kx < 8; ++kx) acc += scratch[kx][rr][dd];
      acc += td2S[rr][0] * wt4Reg.x + td2S[rr][1] * wt4Reg.y +
             td2S[rr][2] * wt4Reg.z + td2S[rr][3] * wt4Reg.w;
      float zu = 1.0f / (1.0f + expf(-acc));
      zupdS[rr][dd] = zu;
      zver[(size_t)(2 * b + rr) * H + dd] = zu;
    }
    __syncthreads();

    // ---- F: hpart for whall rows u,v from NEW z rows (registers) ----
    {
      int r0 = (ub == vb) ? 1 : 0;  // final z[u] is zupd[1] when u==v
      float f0 = 0.0f, f1 = 0.0f;
#pragma unroll
      for (int kk = 0; kk < 16; ++kk) {
        int k = k0 + kk;
        f0 += zupdS[r0][k] * whReg[kk];
        f1 += zupdS[1][k] * whReg[kk];
      }
      scratch[ks][0][d] = f0;
      scratch[ks][1][d] = f1;
    }
    __syncthreads();

    // ---- G: whallv store (t<256) || dlog wave-reductions ([256,768)) ----
    if (t < 2 * H) {
      int rr = t >> 7, dd = t & (H - 1);
      float acc = whbReg;
#pragma unroll
      for (int kx = 0; kx < 8; ++kx) acc += scratch[kx][rr][dd];
      whallv[(size_t)(2 * b + rr) * H + dd] = acc;
    } else if (t < 768) {
      int w = (t - 256) >> 6;  // 8 waves: (row, which)
      int lane = t & 63;
      int row = w >> 2;
      int which = w & 3;  // 0:dL0 1:dR0 2:dL1 3:dR1
      int rr = (row == 0 && ub == vb) ? 1 : row;
      float val = zupdS[rr][lane] * omA + zupdS[rr][64 + lane] * omB;
      for (int s = 32; s > 0; s >>= 1) val += __shfl_down(val, s);
      if (lane == 0) dlog[b * 8 + which * 2 + row] = val;
    }
    __syncthreads();

    if (t == 0) {
      __threadfence();
      atomicOr(&done[b >> 5], 1u << (b & 31));
    }
    return;
  }

  // ================================ LAM ==================================
  const int b = blk - BB;
  const int e = et_[b];
  const int ub = u_[b], vb = v_[b];
  const float ps = psi[e], al = alpha[e], wt = w_t[e];
  const float ob0 = om0_b[0], ob1 = om1_b[0];
  const float ob = e ? ob1 : ob0;
  const float tcur = tt[b];
  const float inv_ps = 1.0f / (ps + 1e-7f);
  const int whichR = 2 * e + 1;  // dR_e
  const int whichL = 2 * e;      // dL_e

  if (t < BB) {
    uS[t] = u_[t];
    vS[t] = v_[t];
  }
  {
    const float4* base = (const float4*)(dvec0 + (size_t)whichR * N);
    float4* dst = (float4*)dR;
    for (int i = t; i < N / 4; i += 1024) dst[i] = base[i];
  }
  // poll all done bits for steps < b (overlapped with staging above)
  if (t == 0) {
    for (int w = 0; w < 4; ++w) {
      int cb = b - 32 * w;
      unsigned nw =
          (cb >= 32) ? 0xffffffffu : (cb <= 0 ? 0u : ((1u << cb) - 1u));
      if (!nw) continue;
      while ((__hip_atomic_load(&done[w], __ATOMIC_RELAXED,
                                __HIP_MEMORY_SCOPE_AGENT) &
              nw) != nw)
        __builtin_amdgcn_s_sleep(1);
    }
    __threadfence();  // acquire
  }
  __syncthreads();

  // apply log updates (steps < b), last-writer filtered so writes are unique
  for (int i = t; i < b; i += 1024) {
    int ui = uS[i], vi = vS[i];
    bool u_over = (ui == vi);
    bool v_over = false;
    for (int j = i + 1; j < b; ++j) {
      int uj = uS[j], vj = vS[j];
      u_over = u_over || (uj == ui) || (vj == ui);
      v_over = v_over || (uj == vi) || (vj == vi);
    }
    if (!u_over) dR[ui] = dlog[i * 8 + whichR * 2 + 0];
    if (!v_over) dR[vi] = dlog[i * 8 + whichR * 2 + 1];
  }

  if (t < 13) {
    auto dpre = [&](int x, int which) -> float {
      for (int bp = b - 1; bp >= 0; --bp) {
        if (vS[bp] == x) return dlog[bp * 8 + which * 2 + 1];
        if (uS[bp] == x) return dlog[bp * 8 + which * 2 + 0];
      }
      return dvec0[(size_t)which * N + x];
    };
    if (t < 11) {
      int li, ri;
      float ltu, ltv;
      if (t == 0) {
        li = ub; ri = vb;
        ltu = t_bar[(size_t)b * N + ub];
        ltv = t_bar[(size_t)b * N + vb];
      } else if (t <= 5) {
        int vn = neg_[b * (2 * KK) + (t - 1)];
        li = ub; ri = vn;
        ltu = t_bar[(size_t)b * N + ub];
        ltv = t_bar[(size_t)b * N + vn];
      } else {
        int un = neg_[b * (2 * KK) + (t - 1)];
        li = un; ri = vb;
        ltu = t_bar[(size_t)b * N + un];
        ltv = t_bar[(size_t)b * N + vb];
      }
      float g = dpre(li, whichL) + dpre(ri, whichR) + ob;
      float gp = fminf(fmaxf(g * inv_ps, -75.0f), 75.0f);
      float ts = tcur - fmaxf(ltu, ltv);
      out[b * 12 + t] = ps * log1pf(expf(gp)) + al * expf(-wt * (ts / TD_MAXF));
    } else if (t == 11) {
      suS = dpre(ub, whichL);
    } else {
      svS = dpre(vb, whichL);
    }
  }
  __syncthreads();

  const float su = suS, sv = svS;
  const float tb_u = t_bar[(size_t)b * N + ub];
  const float tb_v = t_bar[(size_t)b * N + vb];
  const float4* tb4 = (const float4*)(t_bar + (size_t)b * N);
  const float4* dR4 = (const float4*)dR;
  float acc = 0.0f;
  for (int j4 = t; j4 < N / 4; j4 += 1024) {
    float4 dv = dR4[j4];
    float4 tb = tb4[j4];
    float de[4] = {dv.x, dv.y, dv.z, dv.w};
    float te[4] = {tb.x, tb.y, tb.z, tb.w};
#pragma unroll
    for (int ee = 0; ee < 4; ++ee) {
      int j = j4 * 4 + ee;
      if (j == ub || j == vb) continue;
      float dd = de[ee];
      float tbj = te[ee];
      float gu = su + dd + ob;
      float gv = sv + dd + ob;
      float gpu_ = fminf(fmaxf(gu * inv_ps, -75.0f), 75.0f);
      float gpv_ = fminf(fmaxf(gv * inv_ps, -75.0f), 75.0f);
      float spl = ps * (log1pf(expf(gpu_)) + log1pf(expf(gpv_)));
      float tdu = tcur - fmaxf(tb_u, tbj);
      float tdv = tcur - fmaxf(tb_v, tbj);
      float ex =
          al * (expf(-wt * (tdu / TD_MAXF)) + expf(-wt * (tdv / TD_MAXF)));
      acc += spl + ex;
    }
  }
  red[t] = acc;
  __syncthreads();
  for (int s = 512; s > 0; s >>= 1) {
    if (t < s) red[t] += red[t + s];
    __syncthreads();
  }
  if (t == 0) out[b * 12 + 11] = red[0];
}

// ---------------------------------------------------------------------------
extern "C" void kernel_launch(void* const* d_in, const int* in_sizes, int n_in,
                              void* d_out, int out_size, void* d_ws,
                              size_t ws_size, hipStream_t stream) {
  const int* u = (const int*)d_in[0];
  const int* v = (const int*)d_in[1];
  const int* et = (const int*)d_in[2];
  const int* neg = (const int*)d_in[3];
  const float* time_diff = (const float*)d_in[4];
  const float* t_bar = (const float*)d_in[5];
  const float* t = (const float*)d_in[6];
  const float* z0 = (const float*)d_in[7];
  const float* A = (const float*)d_in[8];
  const float* S = (const float*)d_in[9];
  const float* w_t = (const float*)d_in[10];
  const float* alpha = (const float*)d_in[11];
  const float* psi = (const float*)d_in[12];
  const float* om0_w = (const float*)d_in[13];
  const float* om0_b = (const float*)d_in[14];
  const float* om1_w = (const float*)d_in[15];
  const float* om1_b = (const float*)d_in[16];
  const float* Wh_w = (const float*)d_in[17];
  const float* Wh_b = (const float*)d_in[18];
  const float* Ws_w = (const float*)d_in[19];
  const float* Ws_b = (const float*)d_in[20];
  const float* Wr_w = (const float*)d_in[21];
  const float* Wr_b = (const float*)d_in[22];
  const float* Wt_w = (const float*)d_in[23];
  const float* Wt_b = (const float*)d_in[24];
  float* out = (float*)d_out;

  float* wsf = (float*)d_ws;
  float* whall = wsf;                           // N*H (offset 0)
  float* whallv = wsf + OFF_WHALLV;             // 2*BB*H
  float* zver = wsf + OFF_ZVER;                 // 2*BB*H
  float* WhT = zver + 2 * BB * H;               // H*H
  float* WsT = WhT + H * H;                     // H*H
  float* WrT = WsT + H * H;                     // H*H
  float* omP = WrT + H * H;                     // 4*H
  float* dvec0 = omP + 4 * H;                   // 4*N
  float* dlog = dvec0 + 4 * N;                  // 8*BB
  float* qsum = dlog + 8 * BB;                  // 2*BB
  int* cnt = (int*)(qsum + 2 * BB);             // 2*BB
  int* nidx = cnt + 2 * BB;                     // 2*BB*MAXN
  float* nes = (float*)(nidx + 2 * BB * MAXN);  // 2*BB*MAXN
  int* woff = (int*)(nes + 2 * BB * MAXN);      // 2*BB*MAXN
  int* zsrc = woff + 2 * BB * MAXN;             // 2*BB
  unsigned* need = (unsigned*)(zsrc + 2 * BB);  // 4*BB
  unsigned* done = need + 4 * BB;               // 4 (contiguous after need)

  const int PREP_ELEMS = 3 * H * H + 4 * H + 4 * BB + 4 + N;
  prep_all_kernel<<<(PREP_ELEMS + 255) / 256, 256, 0, stream>>>(
      Wh_w, Ws_w, Wr_w, om0_w, om1_w, z0, WhT, WsT, WrT, omP, need, dvec0);
  build_kernel<<<N / 2 + 2 * BB, 256, 0, stream>>>(
      z0, WhT, Wh_b, whall, u, v, A, S, cnt, nidx, nes, qsum, woff, zsrc,
      need);
  fused_kernel<<<2 * BB, 1024, 0, stream>>>(
      u, v, et, neg, time_diff, t_bar, t, z0, WhT, WsT, WrT, omP, Wh_b, Ws_b,
      Wr_b, Wt_w, Wt_b, w_t, alpha, psi, om0_b, om1_b, wsf, zver, whallv,
      dlog, qsum, cnt, nes, woff, zsrc, dvec0, need, done, out);
}